// Round 1
// baseline (2885.959 us; speedup 1.0000x reference)
//
#include <hip/hip_runtime.h>
#include <math.h>

#define BB 4
#define TT 4096
#define NEMB 1024
#define NH 16
#define NKV 8
#define DD 64
#define NCH 64
#define BTOT (BB*TT)
#define ST 68   // LDS row stride for 64-wide tiles (conflict break)

// ---------------------------------------------------------------------------
// GEMM fp32: C[M x N] = A[M x K] @ B[K x N]; BM=BN=128, BK=8, 256 thr, 8x8 micro
// ---------------------------------------------------------------------------
template<int KDIM, int NDIM>
__global__ void __launch_bounds__(256)
gemm_f32(const float* __restrict__ A, const float* __restrict__ Bw,
         float* __restrict__ Cd)
{
  __shared__ float As[8][128];
  __shared__ float Bs[8][128];
  const int tid = threadIdx.x;
  const int bm = blockIdx.y << 7, bn = blockIdx.x << 7;
  const int tx = tid & 15, ty = tid >> 4;
  const int arow = tid >> 1, akq = (tid & 1) << 2;
  const int bkk = tid >> 5, bnq = (tid & 31) << 2;
  float acc[8][8];
#pragma unroll
  for (int i = 0; i < 8; ++i)
#pragma unroll
    for (int j = 0; j < 8; ++j) acc[i][j] = 0.f;

  for (int kt = 0; kt < KDIM; kt += 8) {
    float4 av = *(const float4*)(A + (size_t)(bm + arow)*KDIM + kt + akq);
    float4 bv = *(const float4*)(Bw + (size_t)(kt + bkk)*NDIM + bn + bnq);
    __syncthreads();
    As[akq+0][arow] = av.x; As[akq+1][arow] = av.y;
    As[akq+2][arow] = av.z; As[akq+3][arow] = av.w;
    *(float4*)&Bs[bkk][bnq] = bv;
    __syncthreads();
#pragma unroll
    for (int kk = 0; kk < 8; ++kk) {
      float4 a0 = *(const float4*)&As[kk][ty*8];
      float4 a1 = *(const float4*)&As[kk][ty*8+4];
      float4 b0 = *(const float4*)&Bs[kk][tx*8];
      float4 b1 = *(const float4*)&Bs[kk][tx*8+4];
      float a[8] = {a0.x,a0.y,a0.z,a0.w,a1.x,a1.y,a1.z,a1.w};
      float b[8] = {b0.x,b0.y,b0.z,b0.w,b1.x,b1.y,b1.z,b1.w};
#pragma unroll
      for (int i = 0; i < 8; ++i)
#pragma unroll
        for (int j = 0; j < 8; ++j) acc[i][j] += a[i]*b[j];
    }
  }
#pragma unroll
  for (int i = 0; i < 8; ++i) {
    float4 c0 = make_float4(acc[i][0], acc[i][1], acc[i][2], acc[i][3]);
    float4 c1 = make_float4(acc[i][4], acc[i][5], acc[i][6], acc[i][7]);
    float* dst = Cd + (size_t)(bm + ty*8 + i)*NDIM + bn + tx*8;
    *(float4*)dst = c0;
    *(float4*)(dst + 4) = c1;
  }
}

// ---------------------------------------------------------------------------
// Final GEMM: out = Y @ Wo, where Y (16384x1024) is stored interleaved:
// head h even -> kbuf[(row)*512 + (h/2)*64 + d], h odd -> vbuf[...]
// ---------------------------------------------------------------------------
__global__ void __launch_bounds__(256)
gemm_yout(const float* __restrict__ ybK, const float* __restrict__ ybV,
          const float* __restrict__ Wo, float* __restrict__ Cd)
{
  const int KDIM = 1024, NDIM = 1024;
  __shared__ float As[8][128];
  __shared__ float Bs[8][128];
  const int tid = threadIdx.x;
  const int bm = blockIdx.y << 7, bn = blockIdx.x << 7;
  const int tx = tid & 15, ty = tid >> 4;
  const int arow = tid >> 1, akq = (tid & 1) << 2;
  const int bkk = tid >> 5, bnq = (tid & 31) << 2;
  float acc[8][8];
#pragma unroll
  for (int i = 0; i < 8; ++i)
#pragma unroll
    for (int j = 0; j < 8; ++j) acc[i][j] = 0.f;

  for (int kt = 0; kt < KDIM; kt += 8) {
    const int nidx = kt + akq;               // column in virtual Y
    const float* yb = (nidx & 64) ? ybV : ybK;
    float4 av = *(const float4*)(yb + (size_t)(bm + arow)*512
                                 + ((nidx >> 7) << 6) + (nidx & 63));
    float4 bv = *(const float4*)(Wo + (size_t)(kt + bkk)*NDIM + bn + bnq);
    __syncthreads();
    As[akq+0][arow] = av.x; As[akq+1][arow] = av.y;
    As[akq+2][arow] = av.z; As[akq+3][arow] = av.w;
    *(float4*)&Bs[bkk][bnq] = bv;
    __syncthreads();
#pragma unroll
    for (int kk = 0; kk < 8; ++kk) {
      float4 a0 = *(const float4*)&As[kk][ty*8];
      float4 a1 = *(const float4*)&As[kk][ty*8+4];
      float4 b0 = *(const float4*)&Bs[kk][tx*8];
      float4 b1 = *(const float4*)&Bs[kk][tx*8+4];
      float a[8] = {a0.x,a0.y,a0.z,a0.w,a1.x,a1.y,a1.z,a1.w};
      float b[8] = {b0.x,b0.y,b0.z,b0.w,b1.x,b1.y,b1.z,b1.w};
#pragma unroll
      for (int i = 0; i < 8; ++i)
#pragma unroll
        for (int j = 0; j < 8; ++j) acc[i][j] += a[i]*b[j];
    }
  }
#pragma unroll
  for (int i = 0; i < 8; ++i) {
    float4 c0 = make_float4(acc[i][0], acc[i][1], acc[i][2], acc[i][3]);
    float4 c1 = make_float4(acc[i][4], acc[i][5], acc[i][6], acc[i][7]);
    float* dst = Cd + (size_t)(bm + ty*8 + i)*NDIM + bn + tx*8;
    *(float4*)dst = c0;
    *(float4*)(dst + 4) = c1;
  }
}

// ---------------------------------------------------------------------------
// eta = softplus(x @ lr_w + lr_b)   (BT x 8); one wave per token
// ---------------------------------------------------------------------------
__global__ void __launch_bounds__(256)
eta_kernel(const float* __restrict__ x, const float* __restrict__ lr_w,
           const float* __restrict__ lr_b, float* __restrict__ etab)
{
  __shared__ float lw[NKV*NEMB];   // transposed: [kh][i], 32KB
  const int tid = threadIdx.x;
  for (int idx = tid; idx < NEMB*NKV; idx += 256) {
    int i = idx >> 3, k2 = idx & 7;
    lw[k2*NEMB + i] = lr_w[idx];
  }
  __syncthreads();
  const int w = tid >> 6, lane = tid & 63;
  const size_t tok = (size_t)blockIdx.x*4 + w;
  const float* xr = x + tok*NEMB;
  float acc[8] = {0.f,0.f,0.f,0.f,0.f,0.f,0.f,0.f};
  for (int j = 0; j < 16; ++j) {
    float xv = xr[lane + 64*j];
#pragma unroll
    for (int k2 = 0; k2 < 8; ++k2)
      acc[k2] += xv * lw[k2*NEMB + lane + 64*j];
  }
#pragma unroll
  for (int k2 = 0; k2 < 8; ++k2)
#pragma unroll
    for (int off = 32; off; off >>= 1) acc[k2] += __shfl_xor(acc[k2], off);
  if (lane == 0) {
#pragma unroll
    for (int k2 = 0; k2 < 8; ++k2) {
      float z = acc[k2] + lr_b[k2];
      etab[tok*NKV + k2] = (z > 20.f) ? z : log1pf(expf(z));
    }
  }
}

// ---------------------------------------------------------------------------
// RoPE + RMS in place; one wave per (token, head); nh = 1<<hsh
// ---------------------------------------------------------------------------
__global__ void __launch_bounds__(256)
rope_rms_kernel(float* __restrict__ buf, const float* __restrict__ cosb,
                const float* __restrict__ sinb, int hsh)
{
  const int lane = threadIdx.x & 63;
  const int wid = (blockIdx.x << 2) + (threadIdx.x >> 6);
  const int nh = 1 << hsh;
  const int tok = wid >> hsh;
  const int h = wid & (nh - 1);
  const int t = tok & (TT - 1);
  float* p = buf + (size_t)tok*(nh*DD) + h*DD + lane;
  float v = *p;
  float q = __shfl_xor(v, 32);
  const int dh = lane & 31;
  const float cs = cosb[t*32 + dh], sn = sinb[t*32 + dh];
  float o = (lane < 32) ? (v*cs - q*sn) : (v*cs + q*sn);
  float ss = o*o;
#pragma unroll
  for (int off = 32; off; off >>= 1) ss += __shfl_xor(ss, off);
  *p = o * rsqrtf(ss*(1.f/64) + 1e-6f);
}

// ---------------------------------------------------------------------------
// Chunked TTT scan. One block per (b, kv-head) chain (32 blocks, 256 thr).
// W (64x64) lives in LDS across all 64 chunks. y for head 2kh -> kbuf,
// head 2kh+1 -> vbuf (k/v already consumed into LDS for this chunk).
// ---------------------------------------------------------------------------
__global__ void __launch_bounds__(256, 1)
scan_kernel(const float* __restrict__ qbuf,
            float* __restrict__ kbuf,
            float* __restrict__ vbuf,
            const float* __restrict__ etabuf,
            const float* __restrict__ onw,
            const float* __restrict__ wis_p)
{
  extern __shared__ float sm[];
  float* Ws   = sm;               // [64][ST]  W[d][e]
  float* Kt   = Ws  + 64*ST;      // [64][ST]  k[c][d]
  float* QtT  = Kt  + 64*ST;      // [64][ST]  q^T[d][c]
  float* EsS  = QtT + 64*ST;      // [64][ST]  Es[c][e]
  float* ATs  = EsS + 64*ST;      // [64][ST]  A^T: ATs[j][c] = A[c][j]
  float* rowp = ATs + 64*ST;      // [64][17]
  float* colp = rowp + 64*17;     // [64][5]
  float* ehs  = colp + 64*5;      // [64]
  float* rrd  = ehs + 64;         // [64]
  float* onws = rrd + 64;         // [64]

  const int tid = threadIdx.x;
  const int b  = blockIdx.x >> 3;
  const int kh = blockIdx.x & 7;
  const int tx = tid & 15, ty = tid >> 4;
  const int e0 = tx*4, r0 = ty*4;
  const float wis = *wis_p;

  for (int i = tid; i < 4096; i += 256) {
    int d = i >> 6, e = i & 63;
    Ws[d*ST + e] = (d == e) ? wis : 0.f;
  }
  if (tid < 64) onws[tid] = onw[tid];
  __syncthreads();

  const int ldc = tid >> 2;          // 0..63 cooperative-load row
  const int ldd = (tid & 3) << 4;    // 0,16,32,48

  for (int ch = 0; ch < NCH; ++ch) {
    const size_t rowbase = (size_t)b*TT + (size_t)ch*64;

    { // load K chunk (row-major) + eta
      const float* src = kbuf + (rowbase + ldc)*(NKV*DD) + kh*DD + ldd;
      float4 k0 = *(const float4*)(src + 0);
      float4 k1 = *(const float4*)(src + 4);
      float4 k2 = *(const float4*)(src + 8);
      float4 k3 = *(const float4*)(src + 12);
      *(float4*)&Kt[ldc*ST + ldd + 0]  = k0;
      *(float4*)&Kt[ldc*ST + ldd + 4]  = k1;
      *(float4*)&Kt[ldc*ST + ldd + 8]  = k2;
      *(float4*)&Kt[ldc*ST + ldd + 12] = k3;
      if (tid < 64) ehs[tid] = etabuf[(rowbase + tid)*NKV + kh];
    }
    __syncthreads();

    { // E = k@W - v; Es = eta * E
      float acc[4][4] = {};
      for (int d = 0; d < 64; ++d) {
        float4 wq = *(const float4*)&Ws[d*ST + e0];
        float wv[4] = {wq.x, wq.y, wq.z, wq.w};
        float kv[4];
#pragma unroll
        for (int i = 0; i < 4; ++i) kv[i] = Kt[(r0+i)*ST + d];
#pragma unroll
        for (int i = 0; i < 4; ++i)
#pragma unroll
          for (int j = 0; j < 4; ++j) acc[i][j] += kv[i]*wv[j];
      }
#pragma unroll
      for (int i = 0; i < 4; ++i) {
        float eh = ehs[r0+i];
        float4 vv = *(const float4*)(vbuf + (rowbase + r0+i)*(NKV*DD) + kh*DD + e0);
        float4 r;
        r.x = eh*(acc[i][0] - vv.x);
        r.y = eh*(acc[i][1] - vv.y);
        r.z = eh*(acc[i][2] - vv.z);
        r.w = eh*(acc[i][3] - vv.w);
        *(float4*)&EsS[(r0+i)*ST + e0] = r;
      }
    }
    __syncthreads();

    for (int hh = 0; hh < 2; ++hh) {
      const int h = kh*2 + hh;
      { // load Q^T for this head
        const float* src = qbuf + (rowbase + ldc)*(NH*DD) + h*DD + ldd;
        float4 q0 = *(const float4*)(src + 0);
        float4 q1 = *(const float4*)(src + 4);
        float4 q2 = *(const float4*)(src + 8);
        float4 q3 = *(const float4*)(src + 12);
        QtT[(ldd+ 0)*ST + ldc] = q0.x; QtT[(ldd+ 1)*ST + ldc] = q0.y;
        QtT[(ldd+ 2)*ST + ldc] = q0.z; QtT[(ldd+ 3)*ST + ldc] = q0.w;
        QtT[(ldd+ 4)*ST + ldc] = q1.x; QtT[(ldd+ 5)*ST + ldc] = q1.y;
        QtT[(ldd+ 6)*ST + ldc] = q1.z; QtT[(ldd+ 7)*ST + ldc] = q1.w;
        QtT[(ldd+ 8)*ST + ldc] = q2.x; QtT[(ldd+ 9)*ST + ldc] = q2.y;
        QtT[(ldd+10)*ST + ldc] = q2.z; QtT[(ldd+11)*ST + ldc] = q2.w;
        QtT[(ldd+12)*ST + ldc] = q3.x; QtT[(ldd+13)*ST + ldc] = q3.y;
        QtT[(ldd+14)*ST + ldc] = q3.z; QtT[(ldd+15)*ST + ldc] = q3.w;
      }
      __syncthreads();

      { // A^T pass: ATs[cj][ci] = sum_d k[cj][d] q[ci][d], tril mask (ci>=cj)
        float acc[4][4] = {};
        for (int d = 0; d < 64; ++d) {
          float4 qq = *(const float4*)&QtT[d*ST + e0];
          float qv[4] = {qq.x, qq.y, qq.z, qq.w};
          float kv[4];
#pragma unroll
          for (int i = 0; i < 4; ++i) kv[i] = Kt[(r0+i)*ST + d];
#pragma unroll
          for (int i = 0; i < 4; ++i)
#pragma unroll
            for (int j = 0; j < 4; ++j) acc[i][j] += kv[i]*qv[j];
        }
#pragma unroll
        for (int i = 0; i < 4; ++i) {
          int cj = r0 + i;
          float4 r;
          r.x = (e0+0 >= cj) ? acc[i][0] : 0.f;
          r.y = (e0+1 >= cj) ? acc[i][1] : 0.f;
          r.z = (e0+2 >= cj) ? acc[i][2] : 0.f;
          r.w = (e0+3 >= cj) ? acc[i][3] : 0.f;
          *(float4*)&ATs[cj*ST + e0] = r;
        }
      }
      __syncthreads();

      // out pass: out[c][e] = sum_d q[c][d]W[d][e] - sum_j A[c][j]Es[j][e]
      float acc[4][4] = {};
      {
        for (int d = 0; d < 64; ++d) {
          float4 wq = *(const float4*)&Ws[d*ST + e0];
          float4 qq = *(const float4*)&QtT[d*ST + r0];
          float wv[4] = {wq.x, wq.y, wq.z, wq.w};
          float qv[4] = {qq.x, qq.y, qq.z, qq.w};
#pragma unroll
          for (int i = 0; i < 4; ++i)
#pragma unroll
            for (int j = 0; j < 4; ++j) acc[i][j] += qv[i]*wv[j];
        }
        for (int jj = 0; jj < 64; ++jj) {
          float4 ee = *(const float4*)&EsS[jj*ST + e0];
          float4 aa = *(const float4*)&ATs[jj*ST + r0];
          float ev[4] = {ee.x, ee.y, ee.z, ee.w};
          float av[4] = {aa.x, aa.y, aa.z, aa.w};
#pragma unroll
          for (int i = 0; i < 4; ++i)
#pragma unroll
            for (int j = 0; j < 4; ++j) acc[i][j] -= av[i]*ev[j];
        }
#pragma unroll
        for (int i = 0; i < 4; ++i)
          rowp[(r0+i)*17 + tx] = acc[i][0]*acc[i][0] + acc[i][1]*acc[i][1]
                               + acc[i][2]*acc[i][2] + acc[i][3]*acc[i][3];
      }
      __syncthreads();
      if (tid < 64) {
        float s = 0.f;
#pragma unroll
        for (int x2 = 0; x2 < 16; ++x2) s += rowp[tid*17 + x2];
        rrd[tid] = rsqrtf(s*(1.f/64) + 1e-6f);
      }
      __syncthreads();
      { // scale by rms + out_norm_weight, store y
        float* yb = hh ? vbuf : kbuf;
#pragma unroll
        for (int i = 0; i < 4; ++i) {
          float rr = rrd[r0+i];
          float4 o;
          o.x = acc[i][0]*rr*onws[e0+0];
          o.y = acc[i][1]*rr*onws[e0+1];
          o.z = acc[i][2]*rr*onws[e0+2];
          o.w = acc[i][3]*rr*onws[e0+3];
          *(float4*)(yb + (rowbase + r0+i)*(NKV*DD) + kh*DD + e0) = o;
        }
      }
    }

    { // U = k^T @ Es ; W -= U/64  (rows d=r0.., cols e=e0..)
      float acc[4][4] = {};
      for (int cc = 0; cc < 64; ++cc) {
        float4 kk2 = *(const float4*)&Kt[cc*ST + r0];
        float4 ee  = *(const float4*)&EsS[cc*ST + e0];
        float kv[4] = {kk2.x, kk2.y, kk2.z, kk2.w};
        float ev[4] = {ee.x, ee.y, ee.z, ee.w};
#pragma unroll
        for (int i = 0; i < 4; ++i)
#pragma unroll
          for (int j = 0; j < 4; ++j) acc[i][j] += kv[i]*ev[j];
      }
#pragma unroll
      for (int i = 0; i < 4; ++i) {
        float4 w = *(float4*)&Ws[(r0+i)*ST + e0];
        w.x -= acc[i][0]*(1.f/64);
        w.y -= acc[i][1]*(1.f/64);
        w.z -= acc[i][2]*(1.f/64);
        w.w -= acc[i][3]*(1.f/64);
        *(float4*)&Ws[(r0+i)*ST + e0] = w;
      }
    }
    __syncthreads();

    { // column norms over d
      int e = tid & 63, g = tid >> 6;
      float s = 0.f;
#pragma unroll
      for (int d2 = 0; d2 < 16; ++d2) {
        float w = Ws[(g*16 + d2)*ST + e];
        s += w*w;
      }
      colp[e*5 + g] = s;
    }
    __syncthreads();
    if (tid < 64) {
      float s = colp[tid*5+0] + colp[tid*5+1] + colp[tid*5+2] + colp[tid*5+3];
      rrd[tid] = 1.f / fmaxf(sqrtf(s), 1e-12f);
    }
    __syncthreads();
    {
      float4 rv = *(const float4*)&rrd[e0];
#pragma unroll
      for (int i = 0; i < 4; ++i) {
        float4 w = *(float4*)&Ws[(r0+i)*ST + e0];
        w.x *= rv.x; w.y *= rv.y; w.z *= rv.z; w.w *= rv.w;
        *(float4*)&Ws[(r0+i)*ST + e0] = w;
      }
    }
    __syncthreads();
  }
}

// ---------------------------------------------------------------------------
extern "C" void kernel_launch(void* const* d_in, const int* in_sizes, int n_in,
                              void* d_out, int out_size, void* d_ws, size_t ws_size,
                              hipStream_t stream)
{
  (void)in_sizes; (void)n_in; (void)out_size;
  const float* x    = (const float*)d_in[0];
  const float* cosb = (const float*)d_in[1];
  const float* sinb = (const float*)d_in[2];
  const float* Wq   = (const float*)d_in[3];
  const float* Wk   = (const float*)d_in[4];
  const float* Wv   = (const float*)d_in[5];
  const float* Wo   = (const float*)d_in[6];
  const float* lrw  = (const float*)d_in[7];
  const float* lrb  = (const float*)d_in[8];
  const float* onw  = (const float*)d_in[9];
  const float* wis  = (const float*)d_in[10];
  float* out = (float*)d_out;

  const size_t qN = (size_t)BTOT*NH*DD;    // 16.78M
  const size_t kN = (size_t)BTOT*NKV*DD;   // 8.39M
  const size_t need = (qN + 2*kN + (size_t)BTOT*NKV) * sizeof(float);
  if (ws_size < need) return;   // refuse to scribble OOB

  float* qbuf = (float*)d_ws;
  float* kbuf = qbuf + qN;
  float* vbuf = kbuf + kN;
  float* etab = vbuf + kN;

  gemm_f32<NEMB, NH*DD><<<dim3(8, 128), 256, 0, stream>>>(x, Wq, qbuf);
  gemm_f32<NEMB, NKV*DD><<<dim3(4, 128), 256, 0, stream>>>(x, Wk, kbuf);
  gemm_f32<NEMB, NKV*DD><<<dim3(4, 128), 256, 0, stream>>>(x, Wv, vbuf);
  eta_kernel<<<BTOT/4, 256, 0, stream>>>(x, lrw, lrb, etab);
  rope_rms_kernel<<<(BTOT*NH)/4, 256, 0, stream>>>(qbuf, cosb, sinb, 4);
  rope_rms_kernel<<<(BTOT*NKV)/4, 256, 0, stream>>>(kbuf, cosb, sinb, 3);

  const size_t SMEM = (size_t)(5*64*ST + 64*17 + 64*5 + 3*64) * sizeof(float);
  hipFuncSetAttribute(reinterpret_cast<const void*>(scan_kernel),
                      hipFuncAttributeMaxDynamicSharedMemorySize, (int)SMEM);
  scan_kernel<<<32, 256, SMEM, stream>>>(qbuf, kbuf, vbuf, etab, onw, wis);

  gemm_yout<<<dim3(8, 128), 256, 0, stream>>>(kbuf, vbuf, Wo, out);
}

// Round 2
// 1699.808 us; speedup vs baseline: 1.6978x; 1.6978x over previous
//
#include <hip/hip_runtime.h>
#include <math.h>

#define BB 4
#define TT 4096
#define NEMB 1024
#define NH 16
#define NKV 8
#define DD 64
#define NCH 64
#define BTOT (BB*TT)
#define ST 68    // fp32 LDS row stride (16B-aligned rows: 272B)
#define ST2 72   // bf16 LDS row stride (16B-aligned rows: 144B)

typedef __attribute__((ext_vector_type(8))) __bf16 bf16x8;
typedef __attribute__((ext_vector_type(4))) float f32x4;
typedef unsigned short u16;

__device__ inline u16 f2bf(float f){
  union { float f; unsigned u; } x; x.f = f;
  unsigned r = x.u + 0x7fffu + ((x.u >> 16) & 1u);
  return (u16)(r >> 16);
}

__device__ inline bf16x8 ldfrag(const u16* a, int outer, int k0, int lm, int lh){
  return *(const bf16x8*)(a + (size_t)(outer + lm)*ST2 + k0 + 8*lh);
}

// ---------------------------------------------------------------------------
// GEMM fp32 (unchanged from R1)
// ---------------------------------------------------------------------------
template<int KDIM, int NDIM>
__global__ void __launch_bounds__(256)
gemm_f32(const float* __restrict__ A, const float* __restrict__ Bw,
         float* __restrict__ Cd)
{
  __shared__ float As[8][128];
  __shared__ float Bs[8][128];
  const int tid = threadIdx.x;
  const int bm = blockIdx.y << 7, bn = blockIdx.x << 7;
  const int tx = tid & 15, ty = tid >> 4;
  const int arow = tid >> 1, akq = (tid & 1) << 2;
  const int bkk = tid >> 5, bnq = (tid & 31) << 2;
  float acc[8][8];
#pragma unroll
  for (int i = 0; i < 8; ++i)
#pragma unroll
    for (int j = 0; j < 8; ++j) acc[i][j] = 0.f;

  for (int kt = 0; kt < KDIM; kt += 8) {
    float4 av = *(const float4*)(A + (size_t)(bm + arow)*KDIM + kt + akq);
    float4 bv = *(const float4*)(Bw + (size_t)(kt + bkk)*NDIM + bn + bnq);
    __syncthreads();
    As[akq+0][arow] = av.x; As[akq+1][arow] = av.y;
    As[akq+2][arow] = av.z; As[akq+3][arow] = av.w;
    *(float4*)&Bs[bkk][bnq] = bv;
    __syncthreads();
#pragma unroll
    for (int kk = 0; kk < 8; ++kk) {
      float4 a0 = *(const float4*)&As[kk][ty*8];
      float4 a1 = *(const float4*)&As[kk][ty*8+4];
      float4 b0 = *(const float4*)&Bs[kk][tx*8];
      float4 b1 = *(const float4*)&Bs[kk][tx*8+4];
      float a[8] = {a0.x,a0.y,a0.z,a0.w,a1.x,a1.y,a1.z,a1.w};
      float b[8] = {b0.x,b0.y,b0.z,b0.w,b1.x,b1.y,b1.z,b1.w};
#pragma unroll
      for (int i = 0; i < 8; ++i)
#pragma unroll
        for (int j = 0; j < 8; ++j) acc[i][j] += a[i]*b[j];
    }
  }
#pragma unroll
  for (int i = 0; i < 8; ++i) {
    float4 c0 = make_float4(acc[i][0], acc[i][1], acc[i][2], acc[i][3]);
    float4 c1 = make_float4(acc[i][4], acc[i][5], acc[i][6], acc[i][7]);
    float* dst = Cd + (size_t)(bm + ty*8 + i)*NDIM + bn + tx*8;
    *(float4*)dst = c0;
    *(float4*)(dst + 4) = c1;
  }
}

// ---------------------------------------------------------------------------
// Final GEMM: out = Y @ Wo with Y interleaved in kbuf/vbuf (unchanged)
// ---------------------------------------------------------------------------
__global__ void __launch_bounds__(256)
gemm_yout(const float* __restrict__ ybK, const float* __restrict__ ybV,
          const float* __restrict__ Wo, float* __restrict__ Cd)
{
  const int KDIM = 1024, NDIM = 1024;
  __shared__ float As[8][128];
  __shared__ float Bs[8][128];
  const int tid = threadIdx.x;
  const int bm = blockIdx.y << 7, bn = blockIdx.x << 7;
  const int tx = tid & 15, ty = tid >> 4;
  const int arow = tid >> 1, akq = (tid & 1) << 2;
  const int bkk = tid >> 5, bnq = (tid & 31) << 2;
  float acc[8][8];
#pragma unroll
  for (int i = 0; i < 8; ++i)
#pragma unroll
    for (int j = 0; j < 8; ++j) acc[i][j] = 0.f;

  for (int kt = 0; kt < KDIM; kt += 8) {
    const int nidx = kt + akq;
    const float* yb = (nidx & 64) ? ybV : ybK;
    float4 av = *(const float4*)(yb + (size_t)(bm + arow)*512
                                 + ((nidx >> 7) << 6) + (nidx & 63));
    float4 bv = *(const float4*)(Wo + (size_t)(kt + bkk)*NDIM + bn + bnq);
    __syncthreads();
    As[akq+0][arow] = av.x; As[akq+1][arow] = av.y;
    As[akq+2][arow] = av.z; As[akq+3][arow] = av.w;
    *(float4*)&Bs[bkk][bnq] = bv;
    __syncthreads();
#pragma unroll
    for (int kk = 0; kk < 8; ++kk) {
      float4 a0 = *(const float4*)&As[kk][ty*8];
      float4 a1 = *(const float4*)&As[kk][ty*8+4];
      float4 b0 = *(const float4*)&Bs[kk][tx*8];
      float4 b1 = *(const float4*)&Bs[kk][tx*8+4];
      float a[8] = {a0.x,a0.y,a0.z,a0.w,a1.x,a1.y,a1.z,a1.w};
      float b[8] = {b0.x,b0.y,b0.z,b0.w,b1.x,b1.y,b1.z,b1.w};
#pragma unroll
      for (int i = 0; i < 8; ++i)
#pragma unroll
        for (int j = 0; j < 8; ++j) acc[i][j] += a[i]*b[j];
    }
  }
#pragma unroll
  for (int i = 0; i < 8; ++i) {
    float4 c0 = make_float4(acc[i][0], acc[i][1], acc[i][2], acc[i][3]);
    float4 c1 = make_float4(acc[i][4], acc[i][5], acc[i][6], acc[i][7]);
    float* dst = Cd + (size_t)(bm + ty*8 + i)*NDIM + bn + tx*8;
    *(float4*)dst = c0;
    *(float4*)(dst + 4) = c1;
  }
}

// ---------------------------------------------------------------------------
// eta = softplus(x @ lr_w + lr_b)  (unchanged)
// ---------------------------------------------------------------------------
__global__ void __launch_bounds__(256)
eta_kernel(const float* __restrict__ x, const float* __restrict__ lr_w,
           const float* __restrict__ lr_b, float* __restrict__ etab)
{
  __shared__ float lw[NKV*NEMB];
  const int tid = threadIdx.x;
  for (int idx = tid; idx < NEMB*NKV; idx += 256) {
    int i = idx >> 3, k2 = idx & 7;
    lw[k2*NEMB + i] = lr_w[idx];
  }
  __syncthreads();
  const int w = tid >> 6, lane = tid & 63;
  const size_t tok = (size_t)blockIdx.x*4 + w;
  const float* xr = x + tok*NEMB;
  float acc[8] = {0.f,0.f,0.f,0.f,0.f,0.f,0.f,0.f};
  for (int j = 0; j < 16; ++j) {
    float xv = xr[lane + 64*j];
#pragma unroll
    for (int k2 = 0; k2 < 8; ++k2)
      acc[k2] += xv * lw[k2*NEMB + lane + 64*j];
  }
#pragma unroll
  for (int k2 = 0; k2 < 8; ++k2)
#pragma unroll
    for (int off = 32; off; off >>= 1) acc[k2] += __shfl_xor(acc[k2], off);
  if (lane == 0) {
#pragma unroll
    for (int k2 = 0; k2 < 8; ++k2) {
      float z = acc[k2] + lr_b[k2];
      etab[tok*NKV + k2] = (z > 20.f) ? z : log1pf(expf(z));
    }
  }
}

// ---------------------------------------------------------------------------
// RoPE + RMS in place (unchanged)
// ---------------------------------------------------------------------------
__global__ void __launch_bounds__(256)
rope_rms_kernel(float* __restrict__ buf, const float* __restrict__ cosb,
                const float* __restrict__ sinb, int hsh)
{
  const int lane = threadIdx.x & 63;
  const int wid = (blockIdx.x << 2) + (threadIdx.x >> 6);
  const int nh = 1 << hsh;
  const int tok = wid >> hsh;
  const int h = wid & (nh - 1);
  const int t = tok & (TT - 1);
  float* p = buf + (size_t)tok*(nh*DD) + h*DD + lane;
  float v = *p;
  float q = __shfl_xor(v, 32);
  const int dh = lane & 31;
  const float cs = cosb[t*32 + dh], sn = sinb[t*32 + dh];
  float o = (lane < 32) ? (v*cs - q*sn) : (v*cs + q*sn);
  float ss = o*o;
#pragma unroll
  for (int off = 32; off; off >>= 1) ss += __shfl_xor(ss, off);
  *p = o * rsqrtf(ss*(1.f/64) + 1e-6f);
}

// ---------------------------------------------------------------------------
// MFMA TTT scan. One block per (b, kv-head) chain; 256 threads = 4 waves.
// Per chunk: phase1 {E=K·W, AT_h=K·Q_h^T} -> write negEsT, Ab_h;
// phase2 {Out_h = Q_h·W + A_h·negEs (+RMS, store), U' = K^T·negEs -> W += U'/64};
// then column-norm W and regenerate bf16 W^T.
// MFMA frag layout: A[m][k]: m=l&15, k = k0 + 8*(l>>4)+j (contiguous 8);
// B via transposed storage Bt[n][k] with identical addressing;
// D[m][n]: n=l&15, m = 4*(l>>4)+r  (HW-verified).
// ---------------------------------------------------------------------------
__global__ void __launch_bounds__(256, 1)
scan_mfma(const float* __restrict__ qbuf, float* __restrict__ kbuf,
          float* __restrict__ vbuf, const float* __restrict__ etabuf,
          const float* __restrict__ onw, const float* __restrict__ wis_p)
{
  extern __shared__ char smraw[];
  float* Wf  = (float*)smraw;                 // [64][ST] fp32 master W[d][e]
  float* Vs  = Wf + 64*ST;                    // [64][ST] fp32 V[c][e]
  u16* Kb  = (u16*)(Vs + 64*ST);              // [64][ST2] K[c][d]
  u16* KbT = Kb  + 64*ST2;                    // [64][ST2] K^T[d][c]
  u16* Qb0 = KbT + 64*ST2;                    // [64][ST2] Q_h0[c][d]
  u16* Qb1 = Qb0 + 64*ST2;                    // [64][ST2] Q_h1[c][d]
  u16* EsT = Qb1 + 64*ST2;                    // [64][ST2] negEs^T[e][c]
  u16* Ab0 = EsT + 64*ST2;                    // [64][ST2] A_h0[ci][cj]
  u16* Ab1 = Ab0 + 64*ST2;                    // [64][ST2] A_h1[ci][cj]
  u16* WbT = Ab1 + 64*ST2;                    // [64][ST2] W^T[e][d] bf16
  float* colp = (float*)(WbT + 64*ST2);       // [64][5]
  float* ehs  = colp + 64*5;                  // [64]
  float* rrdc = ehs + 64;                     // [64]
  float* onws = rrdc + 64;                    // [64]

  const int tid = threadIdx.x;
  const int b = blockIdx.x >> 3, kh = blockIdx.x & 7;
  const int w = tid >> 6, l = tid & 63, lm = l & 15, lh = l >> 4;
  const int m0 = w*16;          // this wave's M-row block for every matmul
  const int cb = m0 + lh*4;     // accumulator row base (D-layout)
  const float wis = *wis_p;

  for (int i = tid; i < 4096; i += 256) {
    int d = i >> 6, e = i & 63;
    float v = (d == e) ? wis : 0.f;
    Wf[d*ST + e] = v;
    WbT[e*ST2 + d] = f2bf(v);
  }
  if (tid < 64) onws[tid] = onw[tid];
  __syncthreads();

  const int tc4 = (tid >> 4) * 4;  // c0 for 4x4 coop tile
  const int td4 = (tid & 15) * 4;  // d0
  const int vc = tid >> 2, vq = (tid & 3) * 16;

  for (int ch = 0; ch < NCH; ++ch) {
    const size_t rowbase = (size_t)b*TT + (size_t)ch*64;

    // ---------------- stage0: cooperative loads ----------------
    { // K -> Kb and KbT
      float kv[4][4];
#pragma unroll
      for (int i = 0; i < 4; ++i) {
        float4 t = *(const float4*)(kbuf + (rowbase + tc4 + i)*(NKV*DD) + kh*DD + td4);
        kv[i][0]=t.x; kv[i][1]=t.y; kv[i][2]=t.z; kv[i][3]=t.w;
      }
#pragma unroll
      for (int i = 0; i < 4; ++i) {
        ushort4 u; u.x=f2bf(kv[i][0]); u.y=f2bf(kv[i][1]); u.z=f2bf(kv[i][2]); u.w=f2bf(kv[i][3]);
        *(ushort4*)&Kb[(tc4+i)*ST2 + td4] = u;
      }
#pragma unroll
      for (int j = 0; j < 4; ++j) {
        ushort4 u; u.x=f2bf(kv[0][j]); u.y=f2bf(kv[1][j]); u.z=f2bf(kv[2][j]); u.w=f2bf(kv[3][j]);
        *(ushort4*)&KbT[(td4+j)*ST2 + tc4] = u;
      }
    }
#pragma unroll
    for (int hh = 0; hh < 2; ++hh) { // Q heads -> Qb0/Qb1
      const float* src = qbuf + (rowbase + tc4)*(NH*DD) + (kh*2 + hh)*DD + td4;
      u16* dst = hh ? Qb1 : Qb0;
#pragma unroll
      for (int i = 0; i < 4; ++i) {
        float4 t = *(const float4*)(src + (size_t)i*(NH*DD));
        ushort4 u; u.x=f2bf(t.x); u.y=f2bf(t.y); u.z=f2bf(t.z); u.w=f2bf(t.w);
        *(ushort4*)&dst[(tc4+i)*ST2 + td4] = u;
      }
    }
#pragma unroll
    for (int i = 0; i < 4; ++i)   // V -> Vs (fp32)
      *(float4*)&Vs[vc*ST + vq + i*4] =
        *(const float4*)(vbuf + (rowbase + vc)*(NKV*DD) + kh*DD + vq + i*4);
    if (tid < 64) ehs[tid] = etabuf[(rowbase + tid)*NKV + kh];
    __syncthreads();

    // ---------------- phase1: E and AT (24 MFMA/wave) ----------------
    {
      bf16x8 aK0 = ldfrag(Kb, m0, 0, lm, lh);
      bf16x8 aK1 = ldfrag(Kb, m0, 32, lm, lh);
      f32x4 eac[4], a0c[4], a1c[4];
#pragma unroll
      for (int n = 0; n < 4; ++n) {
        f32x4 z = {0.f,0.f,0.f,0.f};
        eac[n] = z; a0c[n] = z; a1c[n] = z;
      }
#pragma unroll
      for (int n = 0; n < 4; ++n) {
        eac[n] = __builtin_amdgcn_mfma_f32_16x16x32_bf16(aK0, ldfrag(WbT, n*16,  0, lm, lh), eac[n], 0,0,0);
        eac[n] = __builtin_amdgcn_mfma_f32_16x16x32_bf16(aK1, ldfrag(WbT, n*16, 32, lm, lh), eac[n], 0,0,0);
        a0c[n] = __builtin_amdgcn_mfma_f32_16x16x32_bf16(aK0, ldfrag(Qb0, n*16,  0, lm, lh), a0c[n], 0,0,0);
        a0c[n] = __builtin_amdgcn_mfma_f32_16x16x32_bf16(aK1, ldfrag(Qb0, n*16, 32, lm, lh), a0c[n], 0,0,0);
        a1c[n] = __builtin_amdgcn_mfma_f32_16x16x32_bf16(aK0, ldfrag(Qb1, n*16,  0, lm, lh), a1c[n], 0,0,0);
        a1c[n] = __builtin_amdgcn_mfma_f32_16x16x32_bf16(aK1, ldfrag(Qb1, n*16, 32, lm, lh), a1c[n], 0,0,0);
      }
      // negEs = eta * (V - K@W); write negEs^T[e][c] (4 contiguous c per lane)
#pragma unroll
      for (int n = 0; n < 4; ++n) {
        const int e = n*16 + lm;
        ushort4 u;
        u.x = f2bf(ehs[cb+0] * (Vs[(cb+0)*ST + e] - eac[n][0]));
        u.y = f2bf(ehs[cb+1] * (Vs[(cb+1)*ST + e] - eac[n][1]));
        u.z = f2bf(ehs[cb+2] * (Vs[(cb+2)*ST + e] - eac[n][2]));
        u.w = f2bf(ehs[cb+3] * (Vs[(cb+3)*ST + e] - eac[n][3]));
        *(ushort4*)&EsT[e*ST2 + cb] = u;
      }
      // A = tril(Q K^T): from AT accumulators (rows cj=cb+r, cols ci);
      // store A[ci][cj] with 4 contiguous cj per lane
#pragma unroll
      for (int n = 0; n < 4; ++n) {
        const int ci = n*16 + lm;
        ushort4 u0, u1;
        u0.x = f2bf((cb+0 <= ci) ? a0c[n][0] : 0.f);
        u0.y = f2bf((cb+1 <= ci) ? a0c[n][1] : 0.f);
        u0.z = f2bf((cb+2 <= ci) ? a0c[n][2] : 0.f);
        u0.w = f2bf((cb+3 <= ci) ? a0c[n][3] : 0.f);
        u1.x = f2bf((cb+0 <= ci) ? a1c[n][0] : 0.f);
        u1.y = f2bf((cb+1 <= ci) ? a1c[n][1] : 0.f);
        u1.z = f2bf((cb+2 <= ci) ? a1c[n][2] : 0.f);
        u1.w = f2bf((cb+3 <= ci) ? a1c[n][3] : 0.f);
        *(ushort4*)&Ab0[ci*ST2 + cb] = u0;
        *(ushort4*)&Ab1[ci*ST2 + cb] = u1;
      }
    }
    __syncthreads();

    // ---------------- phase2: Out per head + U (40 MFMA/wave) ----------------
    for (int hh = 0; hh < 2; ++hh) {
      const u16* Qb = hh ? Qb1 : Qb0;
      const u16* Ab = hh ? Ab1 : Ab0;
      bf16x8 aQ0 = ldfrag(Qb, m0, 0, lm, lh), aQ1 = ldfrag(Qb, m0, 32, lm, lh);
      bf16x8 aA0 = ldfrag(Ab, m0, 0, lm, lh), aA1 = ldfrag(Ab, m0, 32, lm, lh);
      f32x4 oc[4];
#pragma unroll
      for (int n = 0; n < 4; ++n) {
        f32x4 z = {0.f,0.f,0.f,0.f};
        z = __builtin_amdgcn_mfma_f32_16x16x32_bf16(aQ0, ldfrag(WbT, n*16,  0, lm, lh), z, 0,0,0);
        z = __builtin_amdgcn_mfma_f32_16x16x32_bf16(aQ1, ldfrag(WbT, n*16, 32, lm, lh), z, 0,0,0);
        z = __builtin_amdgcn_mfma_f32_16x16x32_bf16(aA0, ldfrag(EsT, n*16,  0, lm, lh), z, 0,0,0);
        z = __builtin_amdgcn_mfma_f32_16x16x32_bf16(aA1, ldfrag(EsT, n*16, 32, lm, lh), z, 0,0,0);
        oc[n] = z;
      }
      float rr[4];
#pragma unroll
      for (int r = 0; r < 4; ++r) {
        float s = oc[0][r]*oc[0][r] + oc[1][r]*oc[1][r]
                + oc[2][r]*oc[2][r] + oc[3][r]*oc[3][r];
        s += __shfl_xor(s, 1); s += __shfl_xor(s, 2);
        s += __shfl_xor(s, 4); s += __shfl_xor(s, 8);
        rr[r] = rsqrtf(s*(1.f/64.f) + 1e-6f);
      }
      float* yb = hh ? vbuf : kbuf;
#pragma unroll
      for (int n = 0; n < 4; ++n) {
        const int e = n*16 + lm;
        const float ow = onws[e];
#pragma unroll
        for (int r = 0; r < 4; ++r)
          yb[(rowbase + cb + r)*(NKV*DD) + kh*DD + e] = oc[n][r]*rr[r]*ow;
      }
    }
    { // U' = K^T @ negEs ; W += U'/64
      bf16x8 aT0 = ldfrag(KbT, m0, 0, lm, lh), aT1 = ldfrag(KbT, m0, 32, lm, lh);
#pragma unroll
      for (int n = 0; n < 4; ++n) {
        f32x4 z = {0.f,0.f,0.f,0.f};
        z = __builtin_amdgcn_mfma_f32_16x16x32_bf16(aT0, ldfrag(EsT, n*16,  0, lm, lh), z, 0,0,0);
        z = __builtin_amdgcn_mfma_f32_16x16x32_bf16(aT1, ldfrag(EsT, n*16, 32, lm, lh), z, 0,0,0);
        const int e = n*16 + lm;
#pragma unroll
        for (int r = 0; r < 4; ++r)
          Wf[(cb+r)*ST + e] += z[r]*(1.f/64.f);
      }
    }
    __syncthreads();

    // ---------------- column norms + bf16 W^T regen ----------------
    {
      int e = tid & 63, g = tid >> 6;
      float s = 0.f;
#pragma unroll
      for (int d2 = 0; d2 < 16; ++d2) {
        float wv = Wf[(g*16 + d2)*ST + e];
        s += wv*wv;
      }
      colp[e*5 + g] = s;
    }
    __syncthreads();
    if (tid < 64) {
      float s = colp[tid*5+0] + colp[tid*5+1] + colp[tid*5+2] + colp[tid*5+3];
      rrdc[tid] = 1.f / fmaxf(sqrtf(s), 1e-12f);
    }
    __syncthreads();
    {
      const int e0 = (tid & 15)*4, d0 = (tid >> 4)*4;
      float4 rv = *(const float4*)&rrdc[e0];
      float wv[4][4];
#pragma unroll
      for (int i = 0; i < 4; ++i) {
        float4 t = *(float4*)&Wf[(d0+i)*ST + e0];
        t.x *= rv.x; t.y *= rv.y; t.z *= rv.z; t.w *= rv.w;
        *(float4*)&Wf[(d0+i)*ST + e0] = t;
        wv[i][0]=t.x; wv[i][1]=t.y; wv[i][2]=t.z; wv[i][3]=t.w;
      }
#pragma unroll
      for (int j = 0; j < 4; ++j) {
        ushort4 u; u.x=f2bf(wv[0][j]); u.y=f2bf(wv[1][j]); u.z=f2bf(wv[2][j]); u.w=f2bf(wv[3][j]);
        *(ushort4*)&WbT[(e0+j)*ST2 + d0] = u;
      }
    }
    __syncthreads();
  }
}

// ---------------------------------------------------------------------------
extern "C" void kernel_launch(void* const* d_in, const int* in_sizes, int n_in,
                              void* d_out, int out_size, void* d_ws, size_t ws_size,
                              hipStream_t stream)
{
  (void)in_sizes; (void)n_in; (void)out_size;
  const float* x    = (const float*)d_in[0];
  const float* cosb = (const float*)d_in[1];
  const float* sinb = (const float*)d_in[2];
  const float* Wq   = (const float*)d_in[3];
  const float* Wk   = (const float*)d_in[4];
  const float* Wv   = (const float*)d_in[5];
  const float* Wo   = (const float*)d_in[6];
  const float* lrw  = (const float*)d_in[7];
  const float* lrb  = (const float*)d_in[8];
  const float* onw  = (const float*)d_in[9];
  const float* wis  = (const float*)d_in[10];
  float* out = (float*)d_out;

  const size_t qN = (size_t)BTOT*NH*DD;
  const size_t kN = (size_t)BTOT*NKV*DD;
  const size_t need = (qN + 2*kN + (size_t)BTOT*NKV) * sizeof(float);
  if (ws_size < need) return;

  float* qbuf = (float*)d_ws;
  float* kbuf = qbuf + qN;
  float* vbuf = kbuf + kN;
  float* etab = vbuf + kN;

  gemm_f32<NEMB, NH*DD><<<dim3(8, 128), 256, 0, stream>>>(x, Wq, qbuf);
  gemm_f32<NEMB, NKV*DD><<<dim3(4, 128), 256, 0, stream>>>(x, Wk, kbuf);
  gemm_f32<NEMB, NKV*DD><<<dim3(4, 128), 256, 0, stream>>>(x, Wv, vbuf);
  eta_kernel<<<BTOT/4, 256, 0, stream>>>(x, lrw, lrb, etab);
  rope_rms_kernel<<<(BTOT*NH)/4, 256, 0, stream>>>(qbuf, cosb, sinb, 4);
  rope_rms_kernel<<<(BTOT*NKV)/4, 256, 0, stream>>>(kbuf, cosb, sinb, 3);

  const size_t SMEM = (size_t)(2*64*ST)*4 + (size_t)(8*64*ST2)*2
                    + (size_t)(64*5 + 3*64)*4;   // 110592 B
  hipFuncSetAttribute(reinterpret_cast<const void*>(scan_mfma),
                      hipFuncAttributeMaxDynamicSharedMemorySize, (int)SMEM);
  scan_mfma<<<32, 256, SMEM, stream>>>(qbuf, kbuf, vbuf, etab, onw, wis);

  gemm_yout<<<dim3(8, 128), 256, 0, stream>>>(kbuf, vbuf, Wo, out);
}

// Round 5
// 747.807 us; speedup vs baseline: 3.8592x; 2.2731x over previous
//
#include <hip/hip_runtime.h>
#include <math.h>

#define BB 4
#define TT 4096
#define NEMB 1024
#define NH 16
#define NKV 8
#define DD 64
#define NCH 64
#define BTOT (BB*TT)
#define ST 68    // fp32 LDS row stride
#define ST2 72   // bf16 LDS row stride
#define KOFF 1024
#define VOFF 1536
#define GK 1024

typedef __attribute__((ext_vector_type(8))) __bf16 bf16x8;
typedef __attribute__((ext_vector_type(4))) float f32x4;
typedef unsigned short u16;

__device__ inline u16 f2bf(float f){
  union { float f; unsigned u; } x; x.f = f;
  unsigned r = x.u + 0x7fffu + ((x.u >> 16) & 1u);
  return (u16)(r >> 16);
}
__device__ inline float bf2f(u16 u){
  union { unsigned u; float f; } x; x.u = ((unsigned)u) << 16; return x.f;
}
__device__ inline unsigned pk(u16 a, u16 b){ return (unsigned)a | ((unsigned)b << 16); }
__device__ inline bf16x8 ldfrag(const u16* a, int outer, int k0, int lm, int lh){
  return *(const bf16x8*)(a + (size_t)(outer + lm)*ST2 + k0 + 8*lh);
}

// ---------------------------------------------------------------------------
// Weight transpose + hi/lo bf16 split: dsth/dstl[n*1024+k] = split(src[k*N+n])
// ---------------------------------------------------------------------------
__global__ void __launch_bounds__(256)
wt_split(const float* __restrict__ src, u16* __restrict__ dsth,
         u16* __restrict__ dstl, int N)
{
  __shared__ float ts[64][68];
  const int tid = threadIdx.x;
  const int n0 = blockIdx.x*64, k0 = blockIdx.y*64;
  const int tx = tid & 15, ty = tid >> 4;
#pragma unroll
  for (int i = 0; i < 4; ++i) {
    int k = ty + i*16;
    float4 v = *(const float4*)(src + (size_t)(k0+k)*N + n0 + tx*4);
    ts[k][tx*4+0]=v.x; ts[k][tx*4+1]=v.y; ts[k][tx*4+2]=v.z; ts[k][tx*4+3]=v.w;
  }
  __syncthreads();
#pragma unroll
  for (int i = 0; i < 4; ++i) {
    int n = ty + i*16;
    ushort4 uh, ul;
    float f0 = ts[tx*4+0][n], f1 = ts[tx*4+1][n];
    float f2 = ts[tx*4+2][n], f3 = ts[tx*4+3][n];
    uh.x = f2bf(f0); ul.x = f2bf(f0 - bf2f(uh.x));
    uh.y = f2bf(f1); ul.y = f2bf(f1 - bf2f(uh.y));
    uh.z = f2bf(f2); ul.z = f2bf(f2 - bf2f(uh.z));
    uh.w = f2bf(f3); ul.w = f2bf(f3 - bf2f(uh.w));
    *(ushort4*)(dsth + (size_t)(n0+n)*GK + k0 + tx*4) = uh;
    *(ushort4*)(dstl + (size_t)(n0+n)*GK + k0 + tx*4) = ul;
  }
}

// ---------------------------------------------------------------------------
// QKV GEMM, fp32-grade via 3-product split (x hi/lo reg-staged; W hi/lo
// planes via global_load_lds, pre-swizzled source). Epilogue: RoPE+RMS for
// q,k cols (bf16 out); fp32 passthrough for v cols.
// ---------------------------------------------------------------------------
__global__ void __launch_bounds__(256)
gemm_qkv(const float* __restrict__ x,
         const u16* __restrict__ Bth, const u16* __restrict__ Btl,
         u16* __restrict__ qb, u16* __restrict__ kb, float* __restrict__ vb,
         const float* __restrict__ cosb, const float* __restrict__ sinb)
{
  __shared__ u16 AsH[128*64];
  __shared__ u16 AsL[128*64];
  __shared__ u16 BsH[128*64];
  __shared__ u16 BsL[128*64];

  const int tid = threadIdx.x;
  const int w = tid >> 6, l = tid & 63, lm = l & 15, lh = l >> 4;
  const int bm = blockIdx.y << 7, bn = blockIdx.x << 7;
  const int wr = w >> 1, wc = w & 1;

  f32x4 acc[4][4];
#pragma unroll
  for (int i = 0; i < 4; ++i)
#pragma unroll
    for (int j = 0; j < 4; ++j) { f32x4 z = {0.f,0.f,0.f,0.f}; acc[i][j] = z; }

  const int lr8 = l >> 3, sp = l & 7;
  const int ar = tid >> 3, as_ = tid & 7;

  for (int kt = 0; kt < GK; kt += 64) {
    __syncthreads();
#pragma unroll
    for (int c = 0; c < 4; ++c) {
      const int r = (w*4 + c)*8 + lr8;
      const int s = sp ^ (r & 7);
      const u16* gh = Bth + (size_t)(bn + r)*GK + kt + s*8;
      const u16* gl = Btl + (size_t)(bn + r)*GK + kt + s*8;
      __builtin_amdgcn_global_load_lds(
        (const __attribute__((address_space(1))) void*)gh,
        (__attribute__((address_space(3))) void*)(BsH + (w*4 + c)*512), 16, 0, 0);
      __builtin_amdgcn_global_load_lds(
        (const __attribute__((address_space(1))) void*)gl,
        (__attribute__((address_space(3))) void*)(BsL + (w*4 + c)*512), 16, 0, 0);
    }
#pragma unroll
    for (int p = 0; p < 4; ++p) {
      const int r = p*32 + ar;
      const float* gx = x + (size_t)(bm + r)*NEMB + kt + as_*8;
      float4 f0 = *(const float4*)gx;
      float4 f1 = *(const float4*)(gx + 4);
      float fv[8] = {f0.x,f0.y,f0.z,f0.w,f1.x,f1.y,f1.z,f1.w};
      u16 hv[8], lv[8];
#pragma unroll
      for (int j = 0; j < 8; ++j) {
        hv[j] = f2bf(fv[j]);
        lv[j] = f2bf(fv[j] - bf2f(hv[j]));
      }
      uint4 hq, lq;
      hq.x = pk(hv[0],hv[1]); hq.y = pk(hv[2],hv[3]);
      hq.z = pk(hv[4],hv[5]); hq.w = pk(hv[6],hv[7]);
      lq.x = pk(lv[0],lv[1]); lq.y = pk(lv[2],lv[3]);
      lq.z = pk(lv[4],lv[5]); lq.w = pk(lv[6],lv[7]);
      const int off = r*64 + (as_ ^ (r & 7))*8;
      *(uint4*)&AsH[off] = hq;
      *(uint4*)&AsL[off] = lq;
    }
    __syncthreads();
#pragma unroll
    for (int kk = 0; kk < 2; ++kk) {
      bf16x8 ah[4], al[4], bh[4], bl[4];
#pragma unroll
      for (int mi = 0; mi < 4; ++mi) {
        int r = wr*64 + mi*16 + lm;
        int s = (kk*4 + lh) ^ (r & 7);
        ah[mi] = *(const bf16x8*)(AsH + r*64 + s*8);
        al[mi] = *(const bf16x8*)(AsL + r*64 + s*8);
      }
#pragma unroll
      for (int nj = 0; nj < 4; ++nj) {
        int r = wc*64 + nj*16 + lm;
        int s = (kk*4 + lh) ^ (r & 7);
        bh[nj] = *(const bf16x8*)(BsH + r*64 + s*8);
        bl[nj] = *(const bf16x8*)(BsL + r*64 + s*8);
      }
#pragma unroll
      for (int mi = 0; mi < 4; ++mi)
#pragma unroll
        for (int nj = 0; nj < 4; ++nj) {
          acc[mi][nj] = __builtin_amdgcn_mfma_f32_16x16x32_bf16(ah[mi], bh[nj], acc[mi][nj], 0,0,0);
          acc[mi][nj] = __builtin_amdgcn_mfma_f32_16x16x32_bf16(al[mi], bh[nj], acc[mi][nj], 0,0,0);
          acc[mi][nj] = __builtin_amdgcn_mfma_f32_16x16x32_bf16(ah[mi], bl[nj], acc[mi][nj], 0,0,0);
        }
    }
  }

  const int colbase = bn + wc*64;
  if (colbase < VOFF) {
    u16* C; int ldcc, cb2;
    if (colbase < KOFF) { C = qb; ldcc = NH*DD;  cb2 = colbase; }
    else                { C = kb; ldcc = NKV*DD; cb2 = colbase - KOFF; }
#pragma unroll
    for (int mi = 0; mi < 4; ++mi) {
#pragma unroll
      for (int r = 0; r < 4; ++r) {
        const int rl = wr*64 + mi*16 + 4*lh + r;
        const int t = (bm + rl) & (TT - 1);
        const float c0 = cosb[t*32 + lm],      s0 = sinb[t*32 + lm];
        const float c1 = cosb[t*32 + 16 + lm], s1 = sinb[t*32 + 16 + lm];
        float o0 = acc[mi][0][r]*c0 - acc[mi][2][r]*s0;
        float o1 = acc[mi][1][r]*c1 - acc[mi][3][r]*s1;
        float o2 = acc[mi][2][r]*c0 + acc[mi][0][r]*s0;
        float o3 = acc[mi][3][r]*c1 + acc[mi][1][r]*s1;
        float ss = o0*o0 + o1*o1 + o2*o2 + o3*o3;
        ss += __shfl_xor(ss, 1); ss += __shfl_xor(ss, 2);
        ss += __shfl_xor(ss, 4); ss += __shfl_xor(ss, 8);
        const float rr = rsqrtf(ss*(1.f/64.f) + 1e-6f);
        u16* dst = C + (size_t)(bm + rl)*ldcc + cb2 + lm;
        dst[0]  = f2bf(o0*rr);
        dst[16] = f2bf(o1*rr);
        dst[32] = f2bf(o2*rr);
        dst[48] = f2bf(o3*rr);
      }
    }
  } else {
    const int cb2 = colbase - VOFF;
#pragma unroll
    for (int mi = 0; mi < 4; ++mi)
#pragma unroll
      for (int nj = 0; nj < 4; ++nj)
#pragma unroll
        for (int r = 0; r < 4; ++r) {
          const int rl = wr*64 + mi*16 + 4*lh + r;
          vb[(size_t)(bm + rl)*(NKV*DD) + cb2 + nj*16 + lm] = acc[mi][nj][r];
        }
  }
}

// ---------------------------------------------------------------------------
// Out GEMM: out = y @ Wo, fp32-grade via 3-product split.
// y hi plane in Ah (former q slots), lo plane in Al; Wo hi/lo planes.
// ---------------------------------------------------------------------------
__global__ void __launch_bounds__(256)
gemm_out(const u16* __restrict__ Ah, const u16* __restrict__ Al,
         const u16* __restrict__ Bth, const u16* __restrict__ Btl,
         float* __restrict__ C)
{
  __shared__ u16 AsH[128*64];
  __shared__ u16 AsL[128*64];
  __shared__ u16 BsH[128*64];
  __shared__ u16 BsL[128*64];
  const int tid = threadIdx.x;
  const int w = tid >> 6, l = tid & 63, lm = l & 15, lh = l >> 4;
  const int bm = blockIdx.y << 7, bn = blockIdx.x << 7;
  const int wr = w >> 1, wc = w & 1;

  f32x4 acc[4][4];
#pragma unroll
  for (int i = 0; i < 4; ++i)
#pragma unroll
    for (int j = 0; j < 4; ++j) { f32x4 z = {0.f,0.f,0.f,0.f}; acc[i][j] = z; }

  const int lr8 = l >> 3, sp = l & 7;
  for (int kt = 0; kt < GK; kt += 64) {
    __syncthreads();
#pragma unroll
    for (int c = 0; c < 4; ++c) {
      const int r = (w*4 + c)*8 + lr8;
      const int s = sp ^ (r & 7);
      const u16* gah = Ah  + (size_t)(bm + r)*(NH*DD) + kt + s*8;
      const u16* gal = Al  + (size_t)(bm + r)*(NH*DD) + kt + s*8;
      const u16* gbh = Bth + (size_t)(bn + r)*GK      + kt + s*8;
      const u16* gbl = Btl + (size_t)(bn + r)*GK      + kt + s*8;
      __builtin_amdgcn_global_load_lds(
        (const __attribute__((address_space(1))) void*)gah,
        (__attribute__((address_space(3))) void*)(AsH + (w*4 + c)*512), 16, 0, 0);
      __builtin_amdgcn_global_load_lds(
        (const __attribute__((address_space(1))) void*)gal,
        (__attribute__((address_space(3))) void*)(AsL + (w*4 + c)*512), 16, 0, 0);
      __builtin_amdgcn_global_load_lds(
        (const __attribute__((address_space(1))) void*)gbh,
        (__attribute__((address_space(3))) void*)(BsH + (w*4 + c)*512), 16, 0, 0);
      __builtin_amdgcn_global_load_lds(
        (const __attribute__((address_space(1))) void*)gbl,
        (__attribute__((address_space(3))) void*)(BsL + (w*4 + c)*512), 16, 0, 0);
    }
    __syncthreads();
#pragma unroll
    for (int kk = 0; kk < 2; ++kk) {
      bf16x8 ah[4], al[4], bh[4], bl[4];
#pragma unroll
      for (int mi = 0; mi < 4; ++mi) {
        int r = wr*64 + mi*16 + lm;
        int s = (kk*4 + lh) ^ (r & 7);
        ah[mi] = *(const bf16x8*)(AsH + r*64 + s*8);
        al[mi] = *(const bf16x8*)(AsL + r*64 + s*8);
      }
#pragma unroll
      for (int nj = 0; nj < 4; ++nj) {
        int r = wc*64 + nj*16 + lm;
        int s = (kk*4 + lh) ^ (r & 7);
        bh[nj] = *(const bf16x8*)(BsH + r*64 + s*8);
        bl[nj] = *(const bf16x8*)(BsL + r*64 + s*8);
      }
#pragma unroll
      for (int mi = 0; mi < 4; ++mi)
#pragma unroll
        for (int nj = 0; nj < 4; ++nj) {
          acc[mi][nj] = __builtin_amdgcn_mfma_f32_16x16x32_bf16(ah[mi], bh[nj], acc[mi][nj], 0,0,0);
          acc[mi][nj] = __builtin_amdgcn_mfma_f32_16x16x32_bf16(al[mi], bh[nj], acc[mi][nj], 0,0,0);
          acc[mi][nj] = __builtin_amdgcn_mfma_f32_16x16x32_bf16(ah[mi], bl[nj], acc[mi][nj], 0,0,0);
        }
    }
  }
#pragma unroll
  for (int mi = 0; mi < 4; ++mi)
#pragma unroll
    for (int nj = 0; nj < 4; ++nj)
#pragma unroll
      for (int r = 0; r < 4; ++r) {
        const int rl = wr*64 + mi*16 + 4*lh + r;
        C[(size_t)(bm + rl)*NEMB + bn + wc*64 + nj*16 + lm] = acc[mi][nj][r];
      }
}

// ---------------------------------------------------------------------------
// eta = softplus(x @ lr_w + lr_b)  (fp32, unchanged)
// ---------------------------------------------------------------------------
__global__ void __launch_bounds__(256)
eta_kernel(const float* __restrict__ x, const float* __restrict__ lr_w,
           const float* __restrict__ lr_b, float* __restrict__ etab)
{
  __shared__ float lw[NKV*NEMB];
  const int tid = threadIdx.x;
  for (int idx = tid; idx < NEMB*NKV; idx += 256) {
    int i = idx >> 3, k2 = idx & 7;
    lw[k2*NEMB + i] = lr_w[idx];
  }
  __syncthreads();
  const int w = tid >> 6, lane = tid & 63;
  const size_t tok = (size_t)blockIdx.x*4 + w;
  const float* xr = x + tok*NEMB;
  float acc[8] = {0.f,0.f,0.f,0.f,0.f,0.f,0.f,0.f};
  for (int j = 0; j < 16; ++j) {
    float xv = xr[lane + 64*j];
#pragma unroll
    for (int k2 = 0; k2 < 8; ++k2)
      acc[k2] += xv * lw[k2*NEMB + lane + 64*j];
  }
#pragma unroll
  for (int k2 = 0; k2 < 8; ++k2)
#pragma unroll
    for (int off = 32; off; off >>= 1) acc[k2] += __shfl_xor(acc[k2], off);
  if (lane == 0) {
#pragma unroll
    for (int k2 = 0; k2 < 8; ++k2) {
      float z = acc[k2] + lr_b[k2];
      etab[tok*NKV + k2] = (z > 20.f) ? z : log1pf(expf(z));
    }
  }
}

// ---------------------------------------------------------------------------
// MFMA TTT scan (R2-verified numerics). y written as hi/lo bf16 pair:
// hi into the dead q slots of qbuf, lo into ylo.
// ---------------------------------------------------------------------------
__global__ void __launch_bounds__(256, 1)
scan_mfma(u16* __restrict__ qbuf, u16* __restrict__ ylo,
          const u16* __restrict__ kbuf,
          const float* __restrict__ vbuf, const float* __restrict__ etabuf,
          const float* __restrict__ onw, const float* __restrict__ wis_p)
{
  extern __shared__ char smraw[];
  float* Wf  = (float*)smraw;                 // [64][ST] fp32 master W[d][e]
  float* Vs  = Wf + 64*ST;                    // [64][ST] fp32 V[c][e]
  u16* Kb  = (u16*)(Vs + 64*ST);              // [64][ST2] K[c][d]
  u16* KbT = Kb  + 64*ST2;                    // [64][ST2] K^T[d][c]
  u16* Qb0 = KbT + 64*ST2;                    // [64][ST2] Q_h0[c][d]
  u16* Qb1 = Qb0 + 64*ST2;                    // [64][ST2] Q_h1[c][d]
  u16* EsT = Qb1 + 64*ST2;                    // [64][ST2] negEs^T[e][c]
  u16* Ab0 = EsT + 64*ST2;                    // [64][ST2] A_h0[ci][cj]
  u16* Ab1 = Ab0 + 64*ST2;                    // [64][ST2] A_h1[ci][cj]
  u16* WbT = Ab1 + 64*ST2;                    // [64][ST2] W^T[e][d] bf16
  float* colp = (float*)(WbT + 64*ST2);       // [64][5]
  float* ehs  = colp + 64*5;                  // [64]
  float* rrdc = ehs + 64;                     // [64]
  float* onws = rrdc + 64;                    // [64]

  const int tid = threadIdx.x;
  const int b = blockIdx.x >> 3, kh = blockIdx.x & 7;
  const int w = tid >> 6, l = tid & 63, lm = l & 15, lh = l >> 4;
  const int m0 = w*16;
  const int cb = m0 + lh*4;
  const float wis = *wis_p;

  for (int i = tid; i < 4096; i += 256) {
    int d = i >> 6, e = i & 63;
    float v = (d == e) ? wis : 0.f;
    Wf[d*ST + e] = v;
    WbT[e*ST2 + d] = f2bf(v);
  }
  if (tid < 64) onws[tid] = onw[tid];
  __syncthreads();

  const int tc4 = (tid >> 4) * 4;
  const int td4 = (tid & 15) * 4;
  const int vc = tid >> 2, vq = (tid & 3) * 16;

  for (int ch = 0; ch < NCH; ++ch) {
    const size_t rowbase = (size_t)b*TT + (size_t)ch*64;

    // ---------------- stage0 ----------------
    {
      ushort4 t0 = *(const ushort4*)(kbuf + (rowbase+tc4+0)*(NKV*DD) + kh*DD + td4);
      ushort4 t1 = *(const ushort4*)(kbuf + (rowbase+tc4+1)*(NKV*DD) + kh*DD + td4);
      ushort4 t2 = *(const ushort4*)(kbuf + (rowbase+tc4+2)*(NKV*DD) + kh*DD + td4);
      ushort4 t3 = *(const ushort4*)(kbuf + (rowbase+tc4+3)*(NKV*DD) + kh*DD + td4);
      *(ushort4*)&Kb[(tc4+0)*ST2 + td4] = t0;
      *(ushort4*)&Kb[(tc4+1)*ST2 + td4] = t1;
      *(ushort4*)&Kb[(tc4+2)*ST2 + td4] = t2;
      *(ushort4*)&Kb[(tc4+3)*ST2 + td4] = t3;
      ushort4 u;
      u.x=t0.x; u.y=t1.x; u.z=t2.x; u.w=t3.x; *(ushort4*)&KbT[(td4+0)*ST2 + tc4] = u;
      u.x=t0.y; u.y=t1.y; u.z=t2.y; u.w=t3.y; *(ushort4*)&KbT[(td4+1)*ST2 + tc4] = u;
      u.x=t0.z; u.y=t1.z; u.z=t2.z; u.w=t3.z; *(ushort4*)&KbT[(td4+2)*ST2 + tc4] = u;
      u.x=t0.w; u.y=t1.w; u.z=t2.w; u.w=t3.w; *(ushort4*)&KbT[(td4+3)*ST2 + tc4] = u;
    }
#pragma unroll
    for (int hh = 0; hh < 2; ++hh) {
      const u16* src = qbuf + (rowbase + tc4)*(NH*DD) + (kh*2 + hh)*DD + td4;
      u16* dst = hh ? Qb1 : Qb0;
#pragma unroll
      for (int i = 0; i < 4; ++i)
        *(ushort4*)&dst[(tc4+i)*ST2 + td4] = *(const ushort4*)(src + (size_t)i*(NH*DD));
    }
#pragma unroll
    for (int i = 0; i < 4; ++i)
      *(float4*)&Vs[vc*ST + vq + i*4] =
        *(const float4*)(vbuf + (rowbase + vc)*(NKV*DD) + kh*DD + vq + i*4);
    if (tid < 64) ehs[tid] = etabuf[(rowbase + tid)*NKV + kh];
    __syncthreads();

    // ---------------- phase1: E and AT ----------------
    {
      bf16x8 aK0 = ldfrag(Kb, m0, 0, lm, lh);
      bf16x8 aK1 = ldfrag(Kb, m0, 32, lm, lh);
      f32x4 eac[4], a0c[4], a1c[4];
#pragma unroll
      for (int n = 0; n < 4; ++n) {
        f32x4 z = {0.f,0.f,0.f,0.f};
        eac[n] = z; a0c[n] = z; a1c[n] = z;
      }
#pragma unroll
      for (int n = 0; n < 4; ++n) {
        eac[n] = __builtin_amdgcn_mfma_f32_16x16x32_bf16(aK0, ldfrag(WbT, n*16,  0, lm, lh), eac[n], 0,0,0);
        eac[n] = __builtin_amdgcn_mfma_f32_16x16x32_bf16(aK1, ldfrag(WbT, n*16, 32, lm, lh), eac[n], 0,0,0);
        a0c[n] = __builtin_amdgcn_mfma_f32_16x16x32_bf16(aK0, ldfrag(Qb0, n*16,  0, lm, lh), a0c[n], 0,0,0);
        a0c[n] = __builtin_amdgcn_mfma_f32_16x16x32_bf16(aK1, ldfrag(Qb0, n*16, 32, lm, lh), a0c[n], 0,0,0);
        a1c[n] = __builtin_amdgcn_mfma_f32_16x16x32_bf16(aK0, ldfrag(Qb1, n*16,  0, lm, lh), a1c[n], 0,0,0);
        a1c[n] = __builtin_amdgcn_mfma_f32_16x16x32_bf16(aK1, ldfrag(Qb1, n*16, 32, lm, lh), a1c[n], 0,0,0);
      }
#pragma unroll
      for (int n = 0; n < 4; ++n) {
        const int e = n*16 + lm;
        ushort4 u;
        u.x = f2bf(ehs[cb+0] * (Vs[(cb+0)*ST + e] - eac[n][0]));
        u.y = f2bf(ehs[cb+1] * (Vs[(cb+1)*ST + e] - eac[n][1]));
        u.z = f2bf(ehs[cb+2] * (Vs[(cb+2)*ST + e] - eac[n][2]));
        u.w = f2bf(ehs[cb+3] * (Vs[(cb+3)*ST + e] - eac[n][3]));
        *(ushort4*)&EsT[e*ST2 + cb] = u;
      }
#pragma unroll
      for (int n = 0; n < 4; ++n) {
        const int ci = n*16 + lm;
        ushort4 u0, u1;
        u0.x = f2bf((cb+0 <= ci) ? a0c[n][0] : 0.f);
        u0.y = f2bf((cb+1 <= ci) ? a0c[n][1] : 0.f);
        u0.z = f2bf((cb+2 <= ci) ? a0c[n][2] : 0.f);
        u0.w = f2bf((cb+3 <= ci) ? a0c[n][3] : 0.f);
        u1.x = f2bf((cb+0 <= ci) ? a1c[n][0] : 0.f);
        u1.y = f2bf((cb+1 <= ci) ? a1c[n][1] : 0.f);
        u1.z = f2bf((cb+2 <= ci) ? a1c[n][2] : 0.f);
        u1.w = f2bf((cb+3 <= ci) ? a1c[n][3] : 0.f);
        *(ushort4*)&Ab0[ci*ST2 + cb] = u0;
        *(ushort4*)&Ab1[ci*ST2 + cb] = u1;
      }
    }
    __syncthreads();

    // ---------------- phase2: Out per head + U ----------------
    for (int hh = 0; hh < 2; ++hh) {
      const u16* Qb = hh ? Qb1 : Qb0;
      const u16* Ab = hh ? Ab1 : Ab0;
      bf16x8 aQ0 = ldfrag(Qb, m0, 0, lm, lh), aQ1 = ldfrag(Qb, m0, 32, lm, lh);
      bf16x8 aA0 = ldfrag(Ab, m0, 0, lm, lh), aA1 = ldfrag(Ab, m0, 32, lm, lh);
      f32x4 oc[4];
#pragma unroll
      for (int n = 0; n < 4; ++n) {
        f32x4 z = {0.f,0.f,0.f,0.f};
        z = __builtin_amdgcn_mfma_f32_16x16x32_bf16(aQ0, ldfrag(WbT, n*16,  0, lm, lh), z, 0,0,0);
        z = __builtin_amdgcn_mfma_f32_16x16x32_bf16(aQ1, ldfrag(WbT, n*16, 32, lm, lh), z, 0,0,0);
        z = __builtin_amdgcn_mfma_f32_16x16x32_bf16(aA0, ldfrag(EsT, n*16,  0, lm, lh), z, 0,0,0);
        z = __builtin_amdgcn_mfma_f32_16x16x32_bf16(aA1, ldfrag(EsT, n*16, 32, lm, lh), z, 0,0,0);
        oc[n] = z;
      }
      float rr[4];
#pragma unroll
      for (int r = 0; r < 4; ++r) {
        float s = oc[0][r]*oc[0][r] + oc[1][r]*oc[1][r]
                + oc[2][r]*oc[2][r] + oc[3][r]*oc[3][r];
        s += __shfl_xor(s, 1); s += __shfl_xor(s, 2);
        s += __shfl_xor(s, 4); s += __shfl_xor(s, 8);
        rr[r] = rsqrtf(s*(1.f/64.f) + 1e-6f);
      }
      const int ho = (kh*2 + hh)*DD;
#pragma unroll
      for (int n = 0; n < 4; ++n) {
        const int e = n*16 + lm;
        const float ow = onws[e];
#pragma unroll
        for (int r = 0; r < 4; ++r) {
          const size_t idx = (rowbase + cb + r)*(size_t)(NH*DD) + ho + e;
          float val = oc[n][r]*rr[r]*ow;
          u16 hi = f2bf(val);
          qbuf[idx] = hi;
          ylo[idx]  = f2bf(val - bf2f(hi));
        }
      }
    }
    {
      bf16x8 aT0 = ldfrag(KbT, m0, 0, lm, lh), aT1 = ldfrag(KbT, m0, 32, lm, lh);
#pragma unroll
      for (int n = 0; n < 4; ++n) {
        f32x4 z = {0.f,0.f,0.f,0.f};
        z = __builtin_amdgcn_mfma_f32_16x16x32_bf16(aT0, ldfrag(EsT, n*16,  0, lm, lh), z, 0,0,0);
        z = __builtin_amdgcn_mfma_f32_16x16x32_bf16(aT1, ldfrag(EsT, n*16, 32, lm, lh), z, 0,0,0);
        const int e = n*16 + lm;
#pragma unroll
        for (int r = 0; r < 4; ++r)
          Wf[(cb+r)*ST + e] += z[r]*(1.f/64.f);
      }
    }
    __syncthreads();

    // ---------------- column norms + bf16 W^T regen ----------------
    {
      int e = tid & 63, g = tid >> 6;
      float s = 0.f;
#pragma unroll
      for (int d2 = 0; d2 < 16; ++d2) {
        float wv = Wf[(g*16 + d2)*ST + e];
        s += wv*wv;
      }
      colp[e*5 + g] = s;
    }
    __syncthreads();
    if (tid < 64) {
      float s = colp[tid*5+0] + colp[tid*5+1] + colp[tid*5+2] + colp[tid*5+3];
      rrdc[tid] = 1.f / fmaxf(sqrtf(s), 1e-12f);
    }
    __syncthreads();
    {
      const int e0 = (tid & 15)*4, d0 = (tid >> 4)*4;
      float4 rv = *(const float4*)&rrdc[e0];
      float wv[4][4];
#pragma unroll
      for (int i = 0; i < 4; ++i) {
        float4 t = *(float4*)&Wf[(d0+i)*ST + e0];
        t.x *= rv.x; t.y *= rv.y; t.z *= rv.z; t.w *= rv.w;
        *(float4*)&Wf[(d0+i)*ST + e0] = t;
        wv[i][0]=t.x; wv[i][1]=t.y; wv[i][2]=t.z; wv[i][3]=t.w;
      }
#pragma unroll
      for (int j = 0; j < 4; ++j) {
        ushort4 u; u.x=f2bf(wv[0][j]); u.y=f2bf(wv[1][j]); u.z=f2bf(wv[2][j]); u.w=f2bf(wv[3][j]);
        *(ushort4*)&WbT[(e0+j)*ST2 + d0] = u;
      }
    }
    __syncthreads();
  }
}

// ---------------------------------------------------------------------------
extern "C" void kernel_launch(void* const* d_in, const int* in_sizes, int n_in,
                              void* d_out, int out_size, void* d_ws, size_t ws_size,
                              hipStream_t stream)
{
  (void)in_sizes; (void)n_in; (void)out_size;
  const float* x    = (const float*)d_in[0];
  const float* cosb = (const float*)d_in[1];
  const float* sinb = (const float*)d_in[2];
  const float* Wq   = (const float*)d_in[3];
  const float* Wk   = (const float*)d_in[4];
  const float* Wv   = (const float*)d_in[5];
  const float* Wo   = (const float*)d_in[6];
  const float* lrw  = (const float*)d_in[7];
  const float* lrb  = (const float*)d_in[8];
  const float* onw  = (const float*)d_in[9];
  const float* wis  = (const float*)d_in[10];
  float* out = (float*)d_out;

  const size_t qN   = (size_t)BTOT*NH*DD;      // u16 (q, later y_hi)
  const size_t kN   = (size_t)BTOT*NKV*DD;     // u16
  const size_t wtN  = (size_t)2048*GK;         // u16 per plane
  const size_t wotN = (size_t)1024*GK;         // u16 per plane
  const size_t vN   = (size_t)BTOT*NKV*DD;     // f32
  const size_t etaN = (size_t)BTOT*NKV;        // f32
  const size_t need = (qN*2 + kN + wtN*2 + wotN*2)*2 + (vN + etaN)*4;
  if (ws_size < need) return;

  u16* qbuf  = (u16*)d_ws;          // q, then y_hi
  u16* ylo   = qbuf + qN;           // y_lo
  u16* kbuf  = ylo + qN;
  u16* wth   = kbuf + kN;
  u16* wtl   = wth + wtN;
  u16* woth  = wtl + wtN;
  u16* wotl  = woth + wotN;
  float* vbuf = (float*)(wotl + wotN);
  float* etab = vbuf + vN;

  wt_split<<<dim3(16,16), 256, 0, stream>>>(Wq, wth,           wtl,           NH*DD);
  wt_split<<<dim3( 8,16), 256, 0, stream>>>(Wk, wth + 1024*GK, wtl + 1024*GK, NKV*DD);
  wt_split<<<dim3( 8,16), 256, 0, stream>>>(Wv, wth + 1536*GK, wtl + 1536*GK, NKV*DD);
  wt_split<<<dim3(16,16), 256, 0, stream>>>(Wo, woth,          wotl,          NEMB);

  gemm_qkv<<<dim3(16,128), 256, 0, stream>>>(x, wth, wtl, qbuf, kbuf, vbuf, cosb, sinb);
  eta_kernel<<<BTOT/4, 256, 0, stream>>>(x, lrw, lrb, etab);

  const size_t SMEM = (size_t)(2*64*ST)*4 + (size_t)(8*64*ST2)*2
                    + (size_t)(64*5 + 3*64)*4;   // 110592 B
  hipFuncSetAttribute(reinterpret_cast<const void*>(scan_mfma),
                      hipFuncAttributeMaxDynamicSharedMemorySize, (int)SMEM);
  scan_mfma<<<32, 256, SMEM, stream>>>(qbuf, ylo, kbuf, vbuf, etab, onw, wis);

  gemm_out<<<dim3(8,128), 256, 0, stream>>>(qbuf, ylo, woth, wotl, out);
}

// Round 6
// 727.033 us; speedup vs baseline: 3.9695x; 1.0286x over previous
//
#include <hip/hip_runtime.h>
#include <math.h>

#define BB 4
#define TT 4096
#define NEMB 1024
#define NH 16
#define NKV 8
#define DD 64
#define NCH 64
#define BTOT (BB*TT)
#define KOFF 1024
#define VOFF 1536
#define GK 1024
#define ST2 88   // bf16 LDS row stride: 176B = 44 dw == 12 mod 32 -> balanced banks
#define VST 76   // fp32 V stride: 76 dw == 12 mod 32

typedef __attribute__((ext_vector_type(8))) __bf16 bf16x8;
typedef __attribute__((ext_vector_type(4))) float f32x4;
typedef unsigned short u16;

__device__ inline u16 f2bf(float f){
  union { float f; unsigned u; } x; x.f = f;
  unsigned r = x.u + 0x7fffu + ((x.u >> 16) & 1u);
  return (u16)(r >> 16);
}
__device__ inline float bf2f(u16 u){
  union { unsigned u; float f; } x; x.u = ((unsigned)u) << 16; return x.f;
}
__device__ inline unsigned pk(u16 a, u16 b){ return (unsigned)a | ((unsigned)b << 16); }
__device__ inline bf16x8 ldfrag(const u16* a, int outer, int k0, int lm, int lh){
  return *(const bf16x8*)(a + (size_t)(outer + lm)*ST2 + k0 + 8*lh);
}

// ---------------------------------------------------------------------------
// Weight transpose + hi/lo bf16 split (unchanged, proven R5)
// ---------------------------------------------------------------------------
__global__ void __launch_bounds__(256)
wt_split(const float* __restrict__ src, u16* __restrict__ dsth,
         u16* __restrict__ dstl, int N)
{
  __shared__ float ts[64][68];
  const int tid = threadIdx.x;
  const int n0 = blockIdx.x*64, k0 = blockIdx.y*64;
  const int tx = tid & 15, ty = tid >> 4;
#pragma unroll
  for (int i = 0; i < 4; ++i) {
    int k = ty + i*16;
    float4 v = *(const float4*)(src + (size_t)(k0+k)*N + n0 + tx*4);
    ts[k][tx*4+0]=v.x; ts[k][tx*4+1]=v.y; ts[k][tx*4+2]=v.z; ts[k][tx*4+3]=v.w;
  }
  __syncthreads();
#pragma unroll
  for (int i = 0; i < 4; ++i) {
    int n = ty + i*16;
    ushort4 uh, ul;
    float f0 = ts[tx*4+0][n], f1 = ts[tx*4+1][n];
    float f2 = ts[tx*4+2][n], f3 = ts[tx*4+3][n];
    uh.x = f2bf(f0); ul.x = f2bf(f0 - bf2f(uh.x));
    uh.y = f2bf(f1); ul.y = f2bf(f1 - bf2f(uh.y));
    uh.z = f2bf(f2); ul.z = f2bf(f2 - bf2f(uh.z));
    uh.w = f2bf(f3); ul.w = f2bf(f3 - bf2f(uh.w));
    *(ushort4*)(dsth + (size_t)(n0+n)*GK + k0 + tx*4) = uh;
    *(ushort4*)(dstl + (size_t)(n0+n)*GK + k0 + tx*4) = ul;
  }
}

// ---------------------------------------------------------------------------
// QKV GEMM (unchanged, proven R5)
// ---------------------------------------------------------------------------
__global__ void __launch_bounds__(256)
gemm_qkv(const float* __restrict__ x,
         const u16* __restrict__ Bth, const u16* __restrict__ Btl,
         u16* __restrict__ qb, u16* __restrict__ kb, float* __restrict__ vb,
         const float* __restrict__ cosb, const float* __restrict__ sinb)
{
  __shared__ u16 AsH[128*64];
  __shared__ u16 AsL[128*64];
  __shared__ u16 BsH[128*64];
  __shared__ u16 BsL[128*64];

  const int tid = threadIdx.x;
  const int w = tid >> 6, l = tid & 63, lm = l & 15, lh = l >> 4;
  const int bm = blockIdx.y << 7, bn = blockIdx.x << 7;
  const int wr = w >> 1, wc = w & 1;

  f32x4 acc[4][4];
#pragma unroll
  for (int i = 0; i < 4; ++i)
#pragma unroll
    for (int j = 0; j < 4; ++j) { f32x4 z = {0.f,0.f,0.f,0.f}; acc[i][j] = z; }

  const int lr8 = l >> 3, sp = l & 7;
  const int ar = tid >> 3, as_ = tid & 7;

  for (int kt = 0; kt < GK; kt += 64) {
    __syncthreads();
#pragma unroll
    for (int c = 0; c < 4; ++c) {
      const int r = (w*4 + c)*8 + lr8;
      const int s = sp ^ (r & 7);
      const u16* gh = Bth + (size_t)(bn + r)*GK + kt + s*8;
      const u16* gl = Btl + (size_t)(bn + r)*GK + kt + s*8;
      __builtin_amdgcn_global_load_lds(
        (const __attribute__((address_space(1))) void*)gh,
        (__attribute__((address_space(3))) void*)(BsH + (w*4 + c)*512), 16, 0, 0);
      __builtin_amdgcn_global_load_lds(
        (const __attribute__((address_space(1))) void*)gl,
        (__attribute__((address_space(3))) void*)(BsL + (w*4 + c)*512), 16, 0, 0);
    }
#pragma unroll
    for (int p = 0; p < 4; ++p) {
      const int r = p*32 + ar;
      const float* gx = x + (size_t)(bm + r)*NEMB + kt + as_*8;
      float4 f0 = *(const float4*)gx;
      float4 f1 = *(const float4*)(gx + 4);
      float fv[8] = {f0.x,f0.y,f0.z,f0.w,f1.x,f1.y,f1.z,f1.w};
      u16 hv[8], lv[8];
#pragma unroll
      for (int j = 0; j < 8; ++j) {
        hv[j] = f2bf(fv[j]);
        lv[j] = f2bf(fv[j] - bf2f(hv[j]));
      }
      uint4 hq, lq;
      hq.x = pk(hv[0],hv[1]); hq.y = pk(hv[2],hv[3]);
      hq.z = pk(hv[4],hv[5]); hq.w = pk(hv[6],hv[7]);
      lq.x = pk(lv[0],lv[1]); lq.y = pk(lv[2],lv[3]);
      lq.z = pk(lv[4],lv[5]); lq.w = pk(lv[6],lv[7]);
      const int off = r*64 + (as_ ^ (r & 7))*8;
      *(uint4*)&AsH[off] = hq;
      *(uint4*)&AsL[off] = lq;
    }
    __syncthreads();
#pragma unroll
    for (int kk = 0; kk < 2; ++kk) {
      bf16x8 ah[4], al[4], bh[4], bl[4];
#pragma unroll
      for (int mi = 0; mi < 4; ++mi) {
        int r = wr*64 + mi*16 + lm;
        int s = (kk*4 + lh) ^ (r & 7);
        ah[mi] = *(const bf16x8*)(AsH + r*64 + s*8);
        al[mi] = *(const bf16x8*)(AsL + r*64 + s*8);
      }
#pragma unroll
      for (int nj = 0; nj < 4; ++nj) {
        int r = wc*64 + nj*16 + lm;
        int s = (kk*4 + lh) ^ (r & 7);
        bh[nj] = *(const bf16x8*)(BsH + r*64 + s*8);
        bl[nj] = *(const bf16x8*)(BsL + r*64 + s*8);
      }
#pragma unroll
      for (int mi = 0; mi < 4; ++mi)
#pragma unroll
        for (int nj = 0; nj < 4; ++nj) {
          acc[mi][nj] = __builtin_amdgcn_mfma_f32_16x16x32_bf16(ah[mi], bh[nj], acc[mi][nj], 0,0,0);
          acc[mi][nj] = __builtin_amdgcn_mfma_f32_16x16x32_bf16(al[mi], bh[nj], acc[mi][nj], 0,0,0);
          acc[mi][nj] = __builtin_amdgcn_mfma_f32_16x16x32_bf16(ah[mi], bl[nj], acc[mi][nj], 0,0,0);
        }
    }
  }

  const int colbase = bn + wc*64;
  if (colbase < VOFF) {
    u16* C; int ldcc, cb2;
    if (colbase < KOFF) { C = qb; ldcc = NH*DD;  cb2 = colbase; }
    else                { C = kb; ldcc = NKV*DD; cb2 = colbase - KOFF; }
#pragma unroll
    for (int mi = 0; mi < 4; ++mi) {
#pragma unroll
      for (int r = 0; r < 4; ++r) {
        const int rl = wr*64 + mi*16 + 4*lh + r;
        const int t = (bm + rl) & (TT - 1);
        const float c0 = cosb[t*32 + lm],      s0 = sinb[t*32 + lm];
        const float c1 = cosb[t*32 + 16 + lm], s1 = sinb[t*32 + 16 + lm];
        float o0 = acc[mi][0][r]*c0 - acc[mi][2][r]*s0;
        float o1 = acc[mi][1][r]*c1 - acc[mi][3][r]*s1;
        float o2 = acc[mi][2][r]*c0 + acc[mi][0][r]*s0;
        float o3 = acc[mi][3][r]*c1 + acc[mi][1][r]*s1;
        float ss = o0*o0 + o1*o1 + o2*o2 + o3*o3;
        ss += __shfl_xor(ss, 1); ss += __shfl_xor(ss, 2);
        ss += __shfl_xor(ss, 4); ss += __shfl_xor(ss, 8);
        const float rr = rsqrtf(ss*(1.f/64.f) + 1e-6f);
        u16* dst = C + (size_t)(bm + rl)*ldcc + cb2 + lm;
        dst[0]  = f2bf(o0*rr);
        dst[16] = f2bf(o1*rr);
        dst[32] = f2bf(o2*rr);
        dst[48] = f2bf(o3*rr);
      }
    }
  } else {
    const int cb2 = colbase - VOFF;
#pragma unroll
    for (int mi = 0; mi < 4; ++mi)
#pragma unroll
      for (int nj = 0; nj < 4; ++nj)
#pragma unroll
        for (int r = 0; r < 4; ++r) {
          const int rl = wr*64 + mi*16 + 4*lh + r;
          vb[(size_t)(bm + rl)*(NKV*DD) + cb2 + nj*16 + lm] = acc[mi][nj][r];
        }
  }
}

// ---------------------------------------------------------------------------
// Out GEMM (unchanged, proven R5)
// ---------------------------------------------------------------------------
__global__ void __launch_bounds__(256)
gemm_out(const u16* __restrict__ Ah, const u16* __restrict__ Al,
         const u16* __restrict__ Bth, const u16* __restrict__ Btl,
         float* __restrict__ C)
{
  __shared__ u16 AsH[128*64];
  __shared__ u16 AsL[128*64];
  __shared__ u16 BsH[128*64];
  __shared__ u16 BsL[128*64];
  const int tid = threadIdx.x;
  const int w = tid >> 6, l = tid & 63, lm = l & 15, lh = l >> 4;
  const int bm = blockIdx.y << 7, bn = blockIdx.x << 7;
  const int wr = w >> 1, wc = w & 1;

  f32x4 acc[4][4];
#pragma unroll
  for (int i = 0; i < 4; ++i)
#pragma unroll
    for (int j = 0; j < 4; ++j) { f32x4 z = {0.f,0.f,0.f,0.f}; acc[i][j] = z; }

  const int lr8 = l >> 3, sp = l & 7;
  for (int kt = 0; kt < GK; kt += 64) {
    __syncthreads();
#pragma unroll
    for (int c = 0; c < 4; ++c) {
      const int r = (w*4 + c)*8 + lr8;
      const int s = sp ^ (r & 7);
      const u16* gah = Ah  + (size_t)(bm + r)*(NH*DD) + kt + s*8;
      const u16* gal = Al  + (size_t)(bm + r)*(NH*DD) + kt + s*8;
      const u16* gbh = Bth + (size_t)(bn + r)*GK      + kt + s*8;
      const u16* gbl = Btl + (size_t)(bn + r)*GK      + kt + s*8;
      __builtin_amdgcn_global_load_lds(
        (const __attribute__((address_space(1))) void*)gah,
        (__attribute__((address_space(3))) void*)(AsH + (w*4 + c)*512), 16, 0, 0);
      __builtin_amdgcn_global_load_lds(
        (const __attribute__((address_space(1))) void*)gal,
        (__attribute__((address_space(3))) void*)(AsL + (w*4 + c)*512), 16, 0, 0);
      __builtin_amdgcn_global_load_lds(
        (const __attribute__((address_space(1))) void*)gbh,
        (__attribute__((address_space(3))) void*)(BsH + (w*4 + c)*512), 16, 0, 0);
      __builtin_amdgcn_global_load_lds(
        (const __attribute__((address_space(1))) void*)gbl,
        (__attribute__((address_space(3))) void*)(BsL + (w*4 + c)*512), 16, 0, 0);
    }
    __syncthreads();
#pragma unroll
    for (int kk = 0; kk < 2; ++kk) {
      bf16x8 ah[4], al[4], bh[4], bl[4];
#pragma unroll
      for (int mi = 0; mi < 4; ++mi) {
        int r = wr*64 + mi*16 + lm;
        int s = (kk*4 + lh) ^ (r & 7);
        ah[mi] = *(const bf16x8*)(AsH + r*64 + s*8);
        al[mi] = *(const bf16x8*)(AsL + r*64 + s*8);
      }
#pragma unroll
      for (int nj = 0; nj < 4; ++nj) {
        int r = wc*64 + nj*16 + lm;
        int s = (kk*4 + lh) ^ (r & 7);
        bh[nj] = *(const bf16x8*)(BsH + r*64 + s*8);
        bl[nj] = *(const bf16x8*)(BsL + r*64 + s*8);
      }
#pragma unroll
      for (int mi = 0; mi < 4; ++mi)
#pragma unroll
        for (int nj = 0; nj < 4; ++nj) {
          acc[mi][nj] = __builtin_amdgcn_mfma_f32_16x16x32_bf16(ah[mi], bh[nj], acc[mi][nj], 0,0,0);
          acc[mi][nj] = __builtin_amdgcn_mfma_f32_16x16x32_bf16(al[mi], bh[nj], acc[mi][nj], 0,0,0);
          acc[mi][nj] = __builtin_amdgcn_mfma_f32_16x16x32_bf16(ah[mi], bl[nj], acc[mi][nj], 0,0,0);
        }
    }
  }
#pragma unroll
  for (int mi = 0; mi < 4; ++mi)
#pragma unroll
    for (int nj = 0; nj < 4; ++nj)
#pragma unroll
      for (int r = 0; r < 4; ++r) {
        const int rl = wr*64 + mi*16 + 4*lh + r;
        C[(size_t)(bm + rl)*NEMB + bn + wc*64 + nj*16 + lm] = acc[mi][nj][r];
      }
}

// ---------------------------------------------------------------------------
// eta = softplus(x @ lr_w + lr_b)  (unchanged)
// ---------------------------------------------------------------------------
__global__ void __launch_bounds__(256)
eta_kernel(const float* __restrict__ x, const float* __restrict__ lr_w,
           const float* __restrict__ lr_b, float* __restrict__ etab)
{
  __shared__ float lw[NKV*NEMB];
  const int tid = threadIdx.x;
  for (int idx = tid; idx < NEMB*NKV; idx += 256) {
    int i = idx >> 3, k2 = idx & 7;
    lw[k2*NEMB + i] = lr_w[idx];
  }
  __syncthreads();
  const int w = tid >> 6, lane = tid & 63;
  const size_t tok = (size_t)blockIdx.x*4 + w;
  const float* xr = x + tok*NEMB;
  float acc[8] = {0.f,0.f,0.f,0.f,0.f,0.f,0.f,0.f};
  for (int j = 0; j < 16; ++j) {
    float xv = xr[lane + 64*j];
#pragma unroll
    for (int k2 = 0; k2 < 8; ++k2)
      acc[k2] += xv * lw[k2*NEMB + lane + 64*j];
  }
#pragma unroll
  for (int k2 = 0; k2 < 8; ++k2)
#pragma unroll
    for (int off = 32; off; off >>= 1) acc[k2] += __shfl_xor(acc[k2], off);
  if (lane == 0) {
#pragma unroll
    for (int k2 = 0; k2 < 8; ++k2) {
      float z = acc[k2] + lr_b[k2];
      etab[tok*NKV + k2] = (z > 20.f) ? z : log1pf(expf(z));
    }
  }
}

// ---------------------------------------------------------------------------
// MFMA TTT scan, R6: W in registers, fused column-norm, input prefetch (T14),
// bank-balanced stride ST2=88, cached WbT/EsT fragments. 3 barriers/chunk.
// Numerics identical to R5 (verified 0.082).
// ---------------------------------------------------------------------------
__global__ void __launch_bounds__(256, 1)
scan_mfma(u16* __restrict__ qbuf, u16* __restrict__ ylo,
          const u16* __restrict__ kbuf,
          const float* __restrict__ vbuf, const float* __restrict__ etabuf,
          const float* __restrict__ onw, const float* __restrict__ wis_p)
{
  extern __shared__ char smraw[];
  u16* Kb   = (u16*)smraw;            // [64][ST2] K[c][d]
  u16* KbT  = Kb  + 64*ST2;           // [64][ST2] K^T[d][c]
  u16* Qb0  = KbT + 64*ST2;           // [64][ST2] Q_h0[c][d]
  u16* Qb1  = Qb0 + 64*ST2;           // [64][ST2] Q_h1[c][d]
  u16* Ab0  = Qb1 + 64*ST2;           // [64][ST2] A_h0[ci][cj]
  u16* Ab1  = Ab0 + 64*ST2;           // [64][ST2] A_h1[ci][cj]
  u16* EsT  = Ab1 + 64*ST2;           // [64][ST2] negEs^T[e][c]
  u16* WbT  = EsT + 64*ST2;           // [64][ST2] W^T[e][d] bf16
  float* Vs   = (float*)(WbT + 64*ST2); // [64][VST] fp32 V[c][e]
  float* colp = Vs + 64*VST;          // [64][5]
  float* ehs  = colp + 64*5;          // [64]
  float* onws = ehs + 64;             // [64]

  const int tid = threadIdx.x;
  const int b = blockIdx.x >> 3, kh = blockIdx.x & 7;
  const int w = tid >> 6, l = tid & 63, lm = l & 15, lh = l >> 4;
  const int m0 = w*16;
  const int cb = m0 + lh*4;
  const float wis = *wis_p;

  // W master in registers: Wreg[n][r] = W[d=cb+r][e=n*16+lm]
  float Wreg[4][4];
#pragma unroll
  for (int n = 0; n < 4; ++n) {
    const int e = n*16 + lm;
#pragma unroll
    for (int r = 0; r < 4; ++r)
      Wreg[n][r] = ((cb + r) == e) ? wis : 0.f;
    ushort4 u;
    u.x = f2bf(Wreg[n][0]); u.y = f2bf(Wreg[n][1]);
    u.z = f2bf(Wreg[n][2]); u.w = f2bf(Wreg[n][3]);
    *(ushort4*)&WbT[e*ST2 + cb] = u;
  }
  if (tid < 64) onws[tid] = onw[tid];

  const int tc4 = (tid >> 4) * 4;
  const int td4 = (tid & 15) * 4;
  const int vc = tid >> 2, vq = (tid & 3) * 16;

  // prefetch registers
  ushort4 kpre[4], qpre0[4], qpre1[4];
  float4 vpre[4];
  float epre = 0.f;

#define LOAD_PF(CH)                                                            \
  { const size_t rb = (size_t)b*TT + (size_t)(CH)*64;                          \
    _Pragma("unroll")                                                          \
    for (int i = 0; i < 4; ++i) {                                              \
      kpre[i]  = *(const ushort4*)(kbuf + (rb+tc4+i)*(NKV*DD) + kh*DD + td4);  \
      qpre0[i] = *(const ushort4*)(qbuf + (rb+tc4+i)*(NH*DD) + (kh*2)*DD + td4);\
      qpre1[i] = *(const ushort4*)(qbuf + (rb+tc4+i)*(NH*DD) + (kh*2+1)*DD + td4);\
      vpre[i]  = *(const float4*)(vbuf + (rb+vc)*(NKV*DD) + kh*DD + vq + i*4); \
    }                                                                          \
    if (tid < 64) epre = etabuf[(rb + tid)*NKV + kh]; }

#define STAGE0()                                                               \
  { _Pragma("unroll")                                                          \
    for (int i = 0; i < 4; ++i)                                                \
      *(ushort4*)&Kb[(tc4+i)*ST2 + td4] = kpre[i];                             \
    ushort4 u;                                                                 \
    u.x=kpre[0].x; u.y=kpre[1].x; u.z=kpre[2].x; u.w=kpre[3].x;                \
    *(ushort4*)&KbT[(td4+0)*ST2 + tc4] = u;                                    \
    u.x=kpre[0].y; u.y=kpre[1].y; u.z=kpre[2].y; u.w=kpre[3].y;                \
    *(ushort4*)&KbT[(td4+1)*ST2 + tc4] = u;                                    \
    u.x=kpre[0].z; u.y=kpre[1].z; u.z=kpre[2].z; u.w=kpre[3].z;                \
    *(ushort4*)&KbT[(td4+2)*ST2 + tc4] = u;                                    \
    u.x=kpre[0].w; u.y=kpre[1].w; u.z=kpre[2].w; u.w=kpre[3].w;                \
    *(ushort4*)&KbT[(td4+3)*ST2 + tc4] = u;                                    \
    _Pragma("unroll")                                                          \
    for (int i = 0; i < 4; ++i) {                                              \
      *(ushort4*)&Qb0[(tc4+i)*ST2 + td4] = qpre0[i];                           \
      *(ushort4*)&Qb1[(tc4+i)*ST2 + td4] = qpre1[i];                           \
      *(float4*)&Vs[vc*VST + vq + i*4] = vpre[i];                              \
    }                                                                          \
    if (tid < 64) ehs[tid] = epre; }

  LOAD_PF(0);
  STAGE0();
  __syncthreads();

  for (int ch = 0; ch < NCH; ++ch) {
    const size_t rowbase = (size_t)b*TT + (size_t)ch*64;

    if (ch < NCH-1) LOAD_PF(ch+1);

    // ---------------- phase1: E = K*W, AT per head ----------------
    bf16x8 wfr[8];
    {
      bf16x8 aK0 = ldfrag(Kb, m0, 0, lm, lh);
      bf16x8 aK1 = ldfrag(Kb, m0, 32, lm, lh);
      f32x4 eac[4], a0c[4], a1c[4];
#pragma unroll
      for (int n = 0; n < 4; ++n) {
        f32x4 z = {0.f,0.f,0.f,0.f};
        eac[n] = z; a0c[n] = z; a1c[n] = z;
      }
#pragma unroll
      for (int n = 0; n < 4; ++n) {
        wfr[2*n]   = ldfrag(WbT, n*16,  0, lm, lh);
        wfr[2*n+1] = ldfrag(WbT, n*16, 32, lm, lh);
        eac[n] = __builtin_amdgcn_mfma_f32_16x16x32_bf16(aK0, wfr[2*n],   eac[n], 0,0,0);
        eac[n] = __builtin_amdgcn_mfma_f32_16x16x32_bf16(aK1, wfr[2*n+1], eac[n], 0,0,0);
        a0c[n] = __builtin_amdgcn_mfma_f32_16x16x32_bf16(aK0, ldfrag(Qb0, n*16,  0, lm, lh), a0c[n], 0,0,0);
        a0c[n] = __builtin_amdgcn_mfma_f32_16x16x32_bf16(aK1, ldfrag(Qb0, n*16, 32, lm, lh), a0c[n], 0,0,0);
        a1c[n] = __builtin_amdgcn_mfma_f32_16x16x32_bf16(aK0, ldfrag(Qb1, n*16,  0, lm, lh), a1c[n], 0,0,0);
        a1c[n] = __builtin_amdgcn_mfma_f32_16x16x32_bf16(aK1, ldfrag(Qb1, n*16, 32, lm, lh), a1c[n], 0,0,0);
      }
      // negEs = eta * (V - K@W) -> EsT[e][c]
#pragma unroll
      for (int n = 0; n < 4; ++n) {
        const int e = n*16 + lm;
        ushort4 u;
        u.x = f2bf(ehs[cb+0] * (Vs[(cb+0)*VST + e] - eac[n][0]));
        u.y = f2bf(ehs[cb+1] * (Vs[(cb+1)*VST + e] - eac[n][1]));
        u.z = f2bf(ehs[cb+2] * (Vs[(cb+2)*VST + e] - eac[n][2]));
        u.w = f2bf(ehs[cb+3] * (Vs[(cb+3)*VST + e] - eac[n][3]));
        *(ushort4*)&EsT[e*ST2 + cb] = u;
      }
      // A = tril(Q K^T) -> Ab[ci][cj]
#pragma unroll
      for (int n = 0; n < 4; ++n) {
        const int ci = n*16 + lm;
        ushort4 u0, u1;
        u0.x = f2bf((cb+0 <= ci) ? a0c[n][0] : 0.f);
        u0.y = f2bf((cb+1 <= ci) ? a0c[n][1] : 0.f);
        u0.z = f2bf((cb+2 <= ci) ? a0c[n][2] : 0.f);
        u0.w = f2bf((cb+3 <= ci) ? a0c[n][3] : 0.f);
        u1.x = f2bf((cb+0 <= ci) ? a1c[n][0] : 0.f);
        u1.y = f2bf((cb+1 <= ci) ? a1c[n][1] : 0.f);
        u1.z = f2bf((cb+2 <= ci) ? a1c[n][2] : 0.f);
        u1.w = f2bf((cb+3 <= ci) ? a1c[n][3] : 0.f);
        *(ushort4*)&Ab0[ci*ST2 + cb] = u0;
        *(ushort4*)&Ab1[ci*ST2 + cb] = u1;
      }
    }
    __syncthreads();

    // ---------------- phase2: out per head, U, W update, colnorm ----------------
    {
      bf16x8 esf[8];
#pragma unroll
      for (int n = 0; n < 4; ++n) {
        esf[2*n]   = ldfrag(EsT, n*16,  0, lm, lh);
        esf[2*n+1] = ldfrag(EsT, n*16, 32, lm, lh);
      }
#pragma unroll
      for (int hh = 0; hh < 2; ++hh) {
        const u16* Qb = hh ? Qb1 : Qb0;
        const u16* Ab = hh ? Ab1 : Ab0;
        bf16x8 aQ0 = ldfrag(Qb, m0, 0, lm, lh), aQ1 = ldfrag(Qb, m0, 32, lm, lh);
        bf16x8 aA0 = ldfrag(Ab, m0, 0, lm, lh), aA1 = ldfrag(Ab, m0, 32, lm, lh);
        f32x4 oc[4];
#pragma unroll
        for (int n = 0; n < 4; ++n) {
          f32x4 z = {0.f,0.f,0.f,0.f};
          z = __builtin_amdgcn_mfma_f32_16x16x32_bf16(aQ0, wfr[2*n],   z, 0,0,0);
          z = __builtin_amdgcn_mfma_f32_16x16x32_bf16(aQ1, wfr[2*n+1], z, 0,0,0);
          z = __builtin_amdgcn_mfma_f32_16x16x32_bf16(aA0, esf[2*n],   z, 0,0,0);
          z = __builtin_amdgcn_mfma_f32_16x16x32_bf16(aA1, esf[2*n+1], z, 0,0,0);
          oc[n] = z;
        }
        float rr[4];
#pragma unroll
        for (int r = 0; r < 4; ++r) {
          float s = oc[0][r]*oc[0][r] + oc[1][r]*oc[1][r]
                  + oc[2][r]*oc[2][r] + oc[3][r]*oc[3][r];
          s += __shfl_xor(s, 1); s += __shfl_xor(s, 2);
          s += __shfl_xor(s, 4); s += __shfl_xor(s, 8);
          rr[r] = rsqrtf(s*(1.f/64.f) + 1e-6f);
        }
        const int ho = (kh*2 + hh)*DD;
#pragma unroll
        for (int n = 0; n < 4; ++n) {
          const int e = n*16 + lm;
          const float ow = onws[e];
#pragma unroll
          for (int r = 0; r < 4; ++r) {
            const size_t idx = (rowbase + cb + r)*(size_t)(NH*DD) + ho + e;
            float val = oc[n][r]*rr[r]*ow;
            u16 hi = f2bf(val);
            qbuf[idx] = hi;
            ylo[idx]  = f2bf(val - bf2f(hi));
          }
        }
      }
      // U' = K^T @ negEs; W += U'/64; column-norm partials
      bf16x8 aT0 = ldfrag(KbT, m0, 0, lm, lh), aT1 = ldfrag(KbT, m0, 32, lm, lh);
#pragma unroll
      for (int n = 0; n < 4; ++n) {
        f32x4 z = {0.f,0.f,0.f,0.f};
        z = __builtin_amdgcn_mfma_f32_16x16x32_bf16(aT0, esf[2*n],   z, 0,0,0);
        z = __builtin_amdgcn_mfma_f32_16x16x32_bf16(aT1, esf[2*n+1], z, 0,0,0);
        float p = 0.f;
#pragma unroll
        for (int r = 0; r < 4; ++r) {
          Wreg[n][r] += z[r]*(1.f/64.f);
          p += Wreg[n][r]*Wreg[n][r];
        }
        p += __shfl_xor(p, 16);
        p += __shfl_xor(p, 32);
        if (lh == 0) colp[(n*16 + lm)*5 + w] = p;
      }
    }
    __syncthreads();

    // ---------------- finalize: col-norm scale + WbT regen + stage next ----------------
#pragma unroll
    for (int n = 0; n < 4; ++n) {
      const int e = n*16 + lm;
      float s = colp[e*5+0] + colp[e*5+1] + colp[e*5+2] + colp[e*5+3];
      float rv = 1.f / fmaxf(sqrtf(s), 1e-12f);
      ushort4 u;
#pragma unroll
      for (int r = 0; r < 4; ++r) Wreg[n][r] *= rv;
      u.x = f2bf(Wreg[n][0]); u.y = f2bf(Wreg[n][1]);
      u.z = f2bf(Wreg[n][2]); u.w = f2bf(Wreg[n][3]);
      *(ushort4*)&WbT[e*ST2 + cb] = u;
    }
    if (ch < NCH-1) STAGE0();
    __syncthreads();
  }
#undef LOAD_PF
#undef STAGE0
}

// ---------------------------------------------------------------------------
extern "C" void kernel_launch(void* const* d_in, const int* in_sizes, int n_in,
                              void* d_out, int out_size, void* d_ws, size_t ws_size,
                              hipStream_t stream)
{
  (void)in_sizes; (void)n_in; (void)out_size;
  const float* x    = (const float*)d_in[0];
  const float* cosb = (const float*)d_in[1];
  const float* sinb = (const float*)d_in[2];
  const float* Wq   = (const float*)d_in[3];
  const float* Wk   = (const float*)d_in[4];
  const float* Wv   = (const float*)d_in[5];
  const float* Wo   = (const float*)d_in[6];
  const float* lrw  = (const float*)d_in[7];
  const float* lrb  = (const float*)d_in[8];
  const float* onw  = (const float*)d_in[9];
  const float* wis  = (const float*)d_in[10];
  float* out = (float*)d_out;

  const size_t qN   = (size_t)BTOT*NH*DD;      // u16 (q, later y_hi)
  const size_t kN   = (size_t)BTOT*NKV*DD;     // u16
  const size_t wtN  = (size_t)2048*GK;         // u16 per plane
  const size_t wotN = (size_t)1024*GK;         // u16 per plane
  const size_t vN   = (size_t)BTOT*NKV*DD;     // f32
  const size_t etaN = (size_t)BTOT*NKV;        // f32
  const size_t need = (qN*2 + kN + wtN*2 + wotN*2)*2 + (vN + etaN)*4;
  if (ws_size < need) return;

  u16* qbuf  = (u16*)d_ws;          // q, then y_hi
  u16* ylo   = qbuf + qN;           // y_lo
  u16* kbuf  = ylo + qN;
  u16* wth   = kbuf + kN;
  u16* wtl   = wth + wtN;
  u16* woth  = wtl + wtN;
  u16* wotl  = woth + wotN;
  float* vbuf = (float*)(wotl + wotN);
  float* etab = vbuf + vN;

  wt_split<<<dim3(16,16), 256, 0, stream>>>(Wq, wth,           wtl,           NH*DD);
  wt_split<<<dim3( 8,16), 256, 0, stream>>>(Wk, wth + 1024*GK, wtl + 1024*GK, NKV*DD);
  wt_split<<<dim3( 8,16), 256, 0, stream>>>(Wv, wth + 1536*GK, wtl + 1536*GK, NKV*DD);
  wt_split<<<dim3(16,16), 256, 0, stream>>>(Wo, woth,          wotl,          NEMB);

  gemm_qkv<<<dim3(16,128), 256, 0, stream>>>(x, wth, wtl, qbuf, kbuf, vbuf, cosb, sinb);
  eta_kernel<<<BTOT/4, 256, 0, stream>>>(x, lrw, lrb, etab);

  const size_t SMEM = (size_t)(8*64*ST2)*2
                    + (size_t)(64*VST + 64*5 + 64 + 64)*4;   // 111360 B
  hipFuncSetAttribute(reinterpret_cast<const void*>(scan_mfma),
                      hipFuncAttributeMaxDynamicSharedMemorySize, (int)SMEM);
  scan_mfma<<<32, 256, SMEM, stream>>>(qbuf, ylo, kbuf, vbuf, etab, onw, wis);

  gemm_out<<<dim3(8,128), 256, 0, stream>>>(qbuf, ylo, woth, wotl, out);
}

// Round 7
// 660.556 us; speedup vs baseline: 4.3690x; 1.1006x over previous
//
#include <hip/hip_runtime.h>
#include <math.h>

#define BB 4
#define TT 4096
#define NEMB 1024
#define NH 16
#define NKV 8
#define DD 64
#define NCH 64
#define BTOT (BB*TT)
#define KOFF 1024
#define VOFF 1536
#define GK 1024
#define ST2 80   // bf16 LDS row stride: 160B; (2*lm+lh)&7 16B-granule map = balanced

typedef __attribute__((ext_vector_type(8))) __bf16 bf16x8;
typedef __attribute__((ext_vector_type(4))) float f32x4;
typedef unsigned short u16;

__device__ inline u16 f2bf(float f){
  union { float f; unsigned u; } x; x.f = f;
  unsigned r = x.u + 0x7fffu + ((x.u >> 16) & 1u);
  return (u16)(r >> 16);
}
__device__ inline float bf2f(u16 u){
  union { unsigned u; float f; } x; x.u = ((unsigned)u) << 16; return x.f;
}
__device__ inline unsigned pk(u16 a, u16 b){ return (unsigned)a | ((unsigned)b << 16); }
__device__ inline bf16x8 ldfrag(const u16* a, int outer, int k0, int lm, int lh){
  return *(const bf16x8*)(a + (size_t)(outer + lm)*ST2 + k0 + 8*lh);
}

// ---------------------------------------------------------------------------
// Weight transpose + hi/lo bf16 split (unchanged, proven R5)
// ---------------------------------------------------------------------------
__global__ void __launch_bounds__(256)
wt_split(const float* __restrict__ src, u16* __restrict__ dsth,
         u16* __restrict__ dstl, int N)
{
  __shared__ float ts[64][68];
  const int tid = threadIdx.x;
  const int n0 = blockIdx.x*64, k0 = blockIdx.y*64;
  const int tx = tid & 15, ty = tid >> 4;
#pragma unroll
  for (int i = 0; i < 4; ++i) {
    int k = ty + i*16;
    float4 v = *(const float4*)(src + (size_t)(k0+k)*N + n0 + tx*4);
    ts[k][tx*4+0]=v.x; ts[k][tx*4+1]=v.y; ts[k][tx*4+2]=v.z; ts[k][tx*4+3]=v.w;
  }
  __syncthreads();
#pragma unroll
  for (int i = 0; i < 4; ++i) {
    int n = ty + i*16;
    ushort4 uh, ul;
    float f0 = ts[tx*4+0][n], f1 = ts[tx*4+1][n];
    float f2 = ts[tx*4+2][n], f3 = ts[tx*4+3][n];
    uh.x = f2bf(f0); ul.x = f2bf(f0 - bf2f(uh.x));
    uh.y = f2bf(f1); ul.y = f2bf(f1 - bf2f(uh.y));
    uh.z = f2bf(f2); ul.z = f2bf(f2 - bf2f(uh.z));
    uh.w = f2bf(f3); ul.w = f2bf(f3 - bf2f(uh.w));
    *(ushort4*)(dsth + (size_t)(n0+n)*GK + k0 + tx*4) = uh;
    *(ushort4*)(dstl + (size_t)(n0+n)*GK + k0 + tx*4) = ul;
  }
}

// ---------------------------------------------------------------------------
// QKV GEMM (unchanged, proven R5)
// ---------------------------------------------------------------------------
__global__ void __launch_bounds__(256)
gemm_qkv(const float* __restrict__ x,
         const u16* __restrict__ Bth, const u16* __restrict__ Btl,
         u16* __restrict__ qb, u16* __restrict__ kb, float* __restrict__ vb,
         const float* __restrict__ cosb, const float* __restrict__ sinb)
{
  __shared__ u16 AsH[128*64];
  __shared__ u16 AsL[128*64];
  __shared__ u16 BsH[128*64];
  __shared__ u16 BsL[128*64];

  const int tid = threadIdx.x;
  const int w = tid >> 6, l = tid & 63, lm = l & 15, lh = l >> 4;
  const int bm = blockIdx.y << 7, bn = blockIdx.x << 7;
  const int wr = w >> 1, wc = w & 1;

  f32x4 acc[4][4];
#pragma unroll
  for (int i = 0; i < 4; ++i)
#pragma unroll
    for (int j = 0; j < 4; ++j) { f32x4 z = {0.f,0.f,0.f,0.f}; acc[i][j] = z; }

  const int lr8 = l >> 3, sp = l & 7;
  const int ar = tid >> 3, as_ = tid & 7;

  for (int kt = 0; kt < GK; kt += 64) {
    __syncthreads();
#pragma unroll
    for (int c = 0; c < 4; ++c) {
      const int r = (w*4 + c)*8 + lr8;
      const int s = sp ^ (r & 7);
      const u16* gh = Bth + (size_t)(bn + r)*GK + kt + s*8;
      const u16* gl = Btl + (size_t)(bn + r)*GK + kt + s*8;
      __builtin_amdgcn_global_load_lds(
        (const __attribute__((address_space(1))) void*)gh,
        (__attribute__((address_space(3))) void*)(BsH + (w*4 + c)*512), 16, 0, 0);
      __builtin_amdgcn_global_load_lds(
        (const __attribute__((address_space(1))) void*)gl,
        (__attribute__((address_space(3))) void*)(BsL + (w*4 + c)*512), 16, 0, 0);
    }
#pragma unroll
    for (int p = 0; p < 4; ++p) {
      const int r = p*32 + ar;
      const float* gx = x + (size_t)(bm + r)*NEMB + kt + as_*8;
      float4 f0 = *(const float4*)gx;
      float4 f1 = *(const float4*)(gx + 4);
      float fv[8] = {f0.x,f0.y,f0.z,f0.w,f1.x,f1.y,f1.z,f1.w};
      u16 hv[8], lv[8];
#pragma unroll
      for (int j = 0; j < 8; ++j) {
        hv[j] = f2bf(fv[j]);
        lv[j] = f2bf(fv[j] - bf2f(hv[j]));
      }
      uint4 hq, lq;
      hq.x = pk(hv[0],hv[1]); hq.y = pk(hv[2],hv[3]);
      hq.z = pk(hv[4],hv[5]); hq.w = pk(hv[6],hv[7]);
      lq.x = pk(lv[0],lv[1]); lq.y = pk(lv[2],lv[3]);
      lq.z = pk(lv[4],lv[5]); lq.w = pk(lv[6],lv[7]);
      const int off = r*64 + (as_ ^ (r & 7))*8;
      *(uint4*)&AsH[off] = hq;
      *(uint4*)&AsL[off] = lq;
    }
    __syncthreads();
#pragma unroll
    for (int kk = 0; kk < 2; ++kk) {
      bf16x8 ah[4], al[4], bh[4], bl[4];
#pragma unroll
      for (int mi = 0; mi < 4; ++mi) {
        int r = wr*64 + mi*16 + lm;
        int s = (kk*4 + lh) ^ (r & 7);
        ah[mi] = *(const bf16x8*)(AsH + r*64 + s*8);
        al[mi] = *(const bf16x8*)(AsL + r*64 + s*8);
      }
#pragma unroll
      for (int nj = 0; nj < 4; ++nj) {
        int r = wc*64 + nj*16 + lm;
        int s = (kk*4 + lh) ^ (r & 7);
        bh[nj] = *(const bf16x8*)(BsH + r*64 + s*8);
        bl[nj] = *(const bf16x8*)(BsL + r*64 + s*8);
      }
#pragma unroll
      for (int mi = 0; mi < 4; ++mi)
#pragma unroll
        for (int nj = 0; nj < 4; ++nj) {
          acc[mi][nj] = __builtin_amdgcn_mfma_f32_16x16x32_bf16(ah[mi], bh[nj], acc[mi][nj], 0,0,0);
          acc[mi][nj] = __builtin_amdgcn_mfma_f32_16x16x32_bf16(al[mi], bh[nj], acc[mi][nj], 0,0,0);
          acc[mi][nj] = __builtin_amdgcn_mfma_f32_16x16x32_bf16(ah[mi], bl[nj], acc[mi][nj], 0,0,0);
        }
    }
  }

  const int colbase = bn + wc*64;
  if (colbase < VOFF) {
    u16* C; int ldcc, cb2;
    if (colbase < KOFF) { C = qb; ldcc = NH*DD;  cb2 = colbase; }
    else                { C = kb; ldcc = NKV*DD; cb2 = colbase - KOFF; }
#pragma unroll
    for (int mi = 0; mi < 4; ++mi) {
#pragma unroll
      for (int r = 0; r < 4; ++r) {
        const int rl = wr*64 + mi*16 + 4*lh + r;
        const int t = (bm + rl) & (TT - 1);
        const float c0 = cosb[t*32 + lm],      s0 = sinb[t*32 + lm];
        const float c1 = cosb[t*32 + 16 + lm], s1 = sinb[t*32 + 16 + lm];
        float o0 = acc[mi][0][r]*c0 - acc[mi][2][r]*s0;
        float o1 = acc[mi][1][r]*c1 - acc[mi][3][r]*s1;
        float o2 = acc[mi][2][r]*c0 + acc[mi][0][r]*s0;
        float o3 = acc[mi][3][r]*c1 + acc[mi][1][r]*s1;
        float ss = o0*o0 + o1*o1 + o2*o2 + o3*o3;
        ss += __shfl_xor(ss, 1); ss += __shfl_xor(ss, 2);
        ss += __shfl_xor(ss, 4); ss += __shfl_xor(ss, 8);
        const float rr = rsqrtf(ss*(1.f/64.f) + 1e-6f);
        u16* dst = C + (size_t)(bm + rl)*ldcc + cb2 + lm;
        dst[0]  = f2bf(o0*rr);
        dst[16] = f2bf(o1*rr);
        dst[32] = f2bf(o2*rr);
        dst[48] = f2bf(o3*rr);
      }
    }
  } else {
    const int cb2 = colbase - VOFF;
#pragma unroll
    for (int mi = 0; mi < 4; ++mi)
#pragma unroll
      for (int nj = 0; nj < 4; ++nj)
#pragma unroll
        for (int r = 0; r < 4; ++r) {
          const int rl = wr*64 + mi*16 + 4*lh + r;
          vb[(size_t)(bm + rl)*(NKV*DD) + cb2 + nj*16 + lm] = acc[mi][nj][r];
        }
  }
}

// ---------------------------------------------------------------------------
// Out GEMM (unchanged, proven R5)
// ---------------------------------------------------------------------------
__global__ void __launch_bounds__(256)
gemm_out(const u16* __restrict__ Ah, const u16* __restrict__ Al,
         const u16* __restrict__ Bth, const u16* __restrict__ Btl,
         float* __restrict__ C)
{
  __shared__ u16 AsH[128*64];
  __shared__ u16 AsL[128*64];
  __shared__ u16 BsH[128*64];
  __shared__ u16 BsL[128*64];
  const int tid = threadIdx.x;
  const int w = tid >> 6, l = tid & 63, lm = l & 15, lh = l >> 4;
  const int bm = blockIdx.y << 7, bn = blockIdx.x << 7;
  const int wr = w >> 1, wc = w & 1;

  f32x4 acc[4][4];
#pragma unroll
  for (int i = 0; i < 4; ++i)
#pragma unroll
    for (int j = 0; j < 4; ++j) { f32x4 z = {0.f,0.f,0.f,0.f}; acc[i][j] = z; }

  const int lr8 = l >> 3, sp = l & 7;
  for (int kt = 0; kt < GK; kt += 64) {
    __syncthreads();
#pragma unroll
    for (int c = 0; c < 4; ++c) {
      const int r = (w*4 + c)*8 + lr8;
      const int s = sp ^ (r & 7);
      const u16* gah = Ah  + (size_t)(bm + r)*(NH*DD) + kt + s*8;
      const u16* gal = Al  + (size_t)(bm + r)*(NH*DD) + kt + s*8;
      const u16* gbh = Bth + (size_t)(bn + r)*GK      + kt + s*8;
      const u16* gbl = Btl + (size_t)(bn + r)*GK      + kt + s*8;
      __builtin_amdgcn_global_load_lds(
        (const __attribute__((address_space(1))) void*)gah,
        (__attribute__((address_space(3))) void*)(AsH + (w*4 + c)*512), 16, 0, 0);
      __builtin_amdgcn_global_load_lds(
        (const __attribute__((address_space(1))) void*)gal,
        (__attribute__((address_space(3))) void*)(AsL + (w*4 + c)*512), 16, 0, 0);
      __builtin_amdgcn_global_load_lds(
        (const __attribute__((address_space(1))) void*)gbh,
        (__attribute__((address_space(3))) void*)(BsH + (w*4 + c)*512), 16, 0, 0);
      __builtin_amdgcn_global_load_lds(
        (const __attribute__((address_space(1))) void*)gbl,
        (__attribute__((address_space(3))) void*)(BsL + (w*4 + c)*512), 16, 0, 0);
    }
    __syncthreads();
#pragma unroll
    for (int kk = 0; kk < 2; ++kk) {
      bf16x8 ah[4], al[4], bh[4], bl[4];
#pragma unroll
      for (int mi = 0; mi < 4; ++mi) {
        int r = wr*64 + mi*16 + lm;
        int s = (kk*4 + lh) ^ (r & 7);
        ah[mi] = *(const bf16x8*)(AsH + r*64 + s*8);
        al[mi] = *(const bf16x8*)(AsL + r*64 + s*8);
      }
#pragma unroll
      for (int nj = 0; nj < 4; ++nj) {
        int r = wc*64 + nj*16 + lm;
        int s = (kk*4 + lh) ^ (r & 7);
        bh[nj] = *(const bf16x8*)(BsH + r*64 + s*8);
        bl[nj] = *(const bf16x8*)(BsL + r*64 + s*8);
      }
#pragma unroll
      for (int mi = 0; mi < 4; ++mi)
#pragma unroll
        for (int nj = 0; nj < 4; ++nj) {
          acc[mi][nj] = __builtin_amdgcn_mfma_f32_16x16x32_bf16(ah[mi], bh[nj], acc[mi][nj], 0,0,0);
          acc[mi][nj] = __builtin_amdgcn_mfma_f32_16x16x32_bf16(al[mi], bh[nj], acc[mi][nj], 0,0,0);
          acc[mi][nj] = __builtin_amdgcn_mfma_f32_16x16x32_bf16(ah[mi], bl[nj], acc[mi][nj], 0,0,0);
        }
    }
  }
#pragma unroll
  for (int mi = 0; mi < 4; ++mi)
#pragma unroll
    for (int nj = 0; nj < 4; ++nj)
#pragma unroll
      for (int r = 0; r < 4; ++r) {
        const int rl = wr*64 + mi*16 + 4*lh + r;
        C[(size_t)(bm + rl)*NEMB + bn + wc*64 + nj*16 + lm] = acc[mi][nj][r];
      }
}

// ---------------------------------------------------------------------------
// eta = softplus(x @ lr_w + lr_b)  (unchanged)
// ---------------------------------------------------------------------------
__global__ void __launch_bounds__(256)
eta_kernel(const float* __restrict__ x, const float* __restrict__ lr_w,
           const float* __restrict__ lr_b, float* __restrict__ etab)
{
  __shared__ float lw[NKV*NEMB];
  const int tid = threadIdx.x;
  for (int idx = tid; idx < NEMB*NKV; idx += 256) {
    int i = idx >> 3, k2 = idx & 7;
    lw[k2*NEMB + i] = lr_w[idx];
  }
  __syncthreads();
  const int w = tid >> 6, lane = tid & 63;
  const size_t tok = (size_t)blockIdx.x*4 + w;
  const float* xr = x + tok*NEMB;
  float acc[8] = {0.f,0.f,0.f,0.f,0.f,0.f,0.f,0.f};
  for (int j = 0; j < 16; ++j) {
    float xv = xr[lane + 64*j];
#pragma unroll
    for (int k2 = 0; k2 < 8; ++k2)
      acc[k2] += xv * lw[k2*NEMB + lane + 64*j];
  }
#pragma unroll
  for (int k2 = 0; k2 < 8; ++k2)
#pragma unroll
    for (int off = 32; off; off >>= 1) acc[k2] += __shfl_xor(acc[k2], off);
  if (lane == 0) {
#pragma unroll
    for (int k2 = 0; k2 < 8; ++k2) {
      float z = acc[k2] + lr_b[k2];
      etab[tok*NKV + k2] = (z > 20.f) ? z : log1pf(expf(z));
    }
  }
}

// ---------------------------------------------------------------------------
// MFMA TTT scan, R7: 8 waves (512 thr), functional wave split for 2 streams/
// SIMD. Waves 0-3 ("A"): E/Es + out_h0. Waves 4-7 ("B"): QK^T/A + out_h1 +
// W-state + colnorm. V/eta/K-A-frags in registers (T14 prefetch). 7 LDS
// buffers at bank-balanced stride 80. Numerics identical to R5/R6 (0.082).
// ---------------------------------------------------------------------------
__global__ void __launch_bounds__(512, 2)
scan_mfma(u16* __restrict__ qbuf, u16* __restrict__ ylo,
          const u16* __restrict__ kbuf,
          const float* __restrict__ vbuf, const float* __restrict__ etabuf,
          const float* __restrict__ onw, const float* __restrict__ wis_p)
{
  extern __shared__ char smraw[];
  u16* KbT = (u16*)smraw;             // [64][ST2] K^T[d][c]
  u16* Qb0 = KbT + 64*ST2;            // [64][ST2] Q_h0[c][d]
  u16* Qb1 = Qb0 + 64*ST2;            // [64][ST2] Q_h1[c][d]
  u16* Ab0 = Qb1 + 64*ST2;            // [64][ST2] A_h0[ci][cj]
  u16* Ab1 = Ab0 + 64*ST2;            // [64][ST2] A_h1[ci][cj]
  u16* EsT = Ab1 + 64*ST2;            // [64][ST2] negEs^T[e][c]
  u16* WbT = EsT + 64*ST2;            // [64][ST2] W^T[e][d] bf16
  float* colp = (float*)(WbT + 64*ST2); // [64][4]
  float* onws = colp + 64*4;          // [64]

  const int tid = threadIdx.x;
  const int b = blockIdx.x >> 3, kh = blockIdx.x & 7;
  const int w = tid >> 6, l = tid & 63, lm = l & 15, lh = l >> 4;
  const bool gA = (w < 4);
  const int m0 = (w & 3) * 16;
  const int cb = m0 + lh*4;
  const float wis = *wis_p;

  float Wreg[4][4];   // live in group B only
  if (!gA) {
#pragma unroll
    for (int n = 0; n < 4; ++n) {
      const int e = n*16 + lm;
#pragma unroll
      for (int r = 0; r < 4; ++r)
        Wreg[n][r] = ((cb + r) == e) ? wis : 0.f;
      ushort4 u;
      u.x = f2bf(Wreg[n][0]); u.y = f2bf(Wreg[n][1]);
      u.z = f2bf(Wreg[n][2]); u.w = f2bf(Wreg[n][3]);
      *(ushort4*)&WbT[e*ST2 + cb] = u;
    }
  }
  if (tid < 64) onws[tid] = onw[tid];

  const int tc4 = (tid >> 4)*4;   // staging coords (tid<256 only)
  const int td4 = (tid & 15)*4;

  ushort4 kpre[4], qpre0[4], qpre1[4];   // tid<256
  bf16x8 akp0, akp1, ak0, ak1;           // all waves (own frag rows)
  float vpre[4][4], vcur[4][4];          // group A
  float epre[4], ecur[4];                // group A

#define LOAD_PF(CH)                                                            \
  { const size_t rb = (size_t)b*TT + (size_t)(CH)*64;                          \
    if (tid < 256) {                                                           \
      _Pragma("unroll")                                                        \
      for (int i = 0; i < 4; ++i) {                                            \
        kpre[i]  = *(const ushort4*)(kbuf + (rb+tc4+i)*(NKV*DD) + kh*DD + td4);\
        qpre0[i] = *(const ushort4*)(qbuf + (rb+tc4+i)*(NH*DD) + (kh*2)*DD + td4);\
        qpre1[i] = *(const ushort4*)(qbuf + (rb+tc4+i)*(NH*DD) + (kh*2+1)*DD + td4);\
      }                                                                        \
    }                                                                          \
    akp0 = *(const bf16x8*)(kbuf + (rb+m0+lm)*(NKV*DD) + kh*DD + 8*lh);        \
    akp1 = *(const bf16x8*)(kbuf + (rb+m0+lm)*(NKV*DD) + kh*DD + 32 + 8*lh);   \
    if (gA) {                                                                  \
      _Pragma("unroll")                                                        \
      for (int n = 0; n < 4; ++n)                                              \
        _Pragma("unroll")                                                      \
        for (int r = 0; r < 4; ++r)                                            \
          vpre[n][r] = vbuf[(rb+cb+r)*(NKV*DD) + kh*DD + n*16 + lm];           \
      _Pragma("unroll")                                                        \
      for (int r = 0; r < 4; ++r) epre[r] = etabuf[(rb+cb+r)*NKV + kh];        \
    } }

#define PROMOTE()                                                              \
  { ak0 = akp0; ak1 = akp1;                                                    \
    if (gA) {                                                                  \
      _Pragma("unroll")                                                        \
      for (int n = 0; n < 4; ++n)                                              \
        _Pragma("unroll")                                                      \
        for (int r = 0; r < 4; ++r) vcur[n][r] = vpre[n][r];                   \
      _Pragma("unroll")                                                        \
      for (int r = 0; r < 4; ++r) ecur[r] = epre[r];                           \
    }                                                                          \
    if (tid < 256) {                                                           \
      ushort4 u;                                                               \
      u.x=kpre[0].x; u.y=kpre[1].x; u.z=kpre[2].x; u.w=kpre[3].x;              \
      *(ushort4*)&KbT[(td4+0)*ST2 + tc4] = u;                                  \
      u.x=kpre[0].y; u.y=kpre[1].y; u.z=kpre[2].y; u.w=kpre[3].y;              \
      *(ushort4*)&KbT[(td4+1)*ST2 + tc4] = u;                                  \
      u.x=kpre[0].z; u.y=kpre[1].z; u.z=kpre[2].z; u.w=kpre[3].z;              \
      *(ushort4*)&KbT[(td4+2)*ST2 + tc4] = u;                                  \
      u.x=kpre[0].w; u.y=kpre[1].w; u.z=kpre[2].w; u.w=kpre[3].w;              \
      *(ushort4*)&KbT[(td4+3)*ST2 + tc4] = u;                                  \
      _Pragma("unroll")                                                        \
      for (int i = 0; i < 4; ++i) {                                            \
        *(ushort4*)&Qb0[(tc4+i)*ST2 + td4] = qpre0[i];                         \
        *(ushort4*)&Qb1[(tc4+i)*ST2 + td4] = qpre1[i];                         \
      }                                                                        \
    } }

  LOAD_PF(0);
  PROMOTE();
  __syncthreads();

  for (int ch = 0; ch < NCH; ++ch) {
    const size_t rowbase = (size_t)b*TT + (size_t)ch*64;

    if (ch < NCH-1) LOAD_PF(ch+1);

    bf16x8 wfr[8];
    // ---------------- phase1 ----------------
    if (gA) {
      // E = K·W; negEs = eta*(V - E) -> EsT
      f32x4 eac[4];
#pragma unroll
      for (int n = 0; n < 4; ++n) { f32x4 z = {0.f,0.f,0.f,0.f}; eac[n] = z; }
#pragma unroll
      for (int n = 0; n < 4; ++n) {
        wfr[2*n]   = ldfrag(WbT, n*16,  0, lm, lh);
        wfr[2*n+1] = ldfrag(WbT, n*16, 32, lm, lh);
        eac[n] = __builtin_amdgcn_mfma_f32_16x16x32_bf16(ak0, wfr[2*n],   eac[n], 0,0,0);
        eac[n] = __builtin_amdgcn_mfma_f32_16x16x32_bf16(ak1, wfr[2*n+1], eac[n], 0,0,0);
      }
#pragma unroll
      for (int n = 0; n < 4; ++n) {
        const int e = n*16 + lm;
        ushort4 u;
        u.x = f2bf(ecur[0] * (vcur[n][0] - eac[n][0]));
        u.y = f2bf(ecur[1] * (vcur[n][1] - eac[n][1]));
        u.z = f2bf(ecur[2] * (vcur[n][2] - eac[n][2]));
        u.w = f2bf(ecur[3] * (vcur[n][3] - eac[n][3]));
        *(ushort4*)&EsT[e*ST2 + cb] = u;
      }
    } else {
      // AT = K·Q^T both heads; mask tril; -> Ab0/Ab1
      f32x4 a0c[4], a1c[4];
#pragma unroll
      for (int n = 0; n < 4; ++n) { f32x4 z = {0.f,0.f,0.f,0.f}; a0c[n] = z; a1c[n] = z; }
#pragma unroll
      for (int n = 0; n < 4; ++n) {
        a0c[n] = __builtin_amdgcn_mfma_f32_16x16x32_bf16(ak0, ldfrag(Qb0, n*16,  0, lm, lh), a0c[n], 0,0,0);
        a0c[n] = __builtin_amdgcn_mfma_f32_16x16x32_bf16(ak1, ldfrag(Qb0, n*16, 32, lm, lh), a0c[n], 0,0,0);
        a1c[n] = __builtin_amdgcn_mfma_f32_16x16x32_bf16(ak0, ldfrag(Qb1, n*16,  0, lm, lh), a1c[n], 0,0,0);
        a1c[n] = __builtin_amdgcn_mfma_f32_16x16x32_bf16(ak1, ldfrag(Qb1, n*16, 32, lm, lh), a1c[n], 0,0,0);
      }
#pragma unroll
      for (int n = 0; n < 4; ++n) {
        const int ci = n*16 + lm;
        ushort4 u0, u1;
        u0.x = f2bf((cb+0 <= ci) ? a0c[n][0] : 0.f);
        u0.y = f2bf((cb+1 <= ci) ? a0c[n][1] : 0.f);
        u0.z = f2bf((cb+2 <= ci) ? a0c[n][2] : 0.f);
        u0.w = f2bf((cb+3 <= ci) ? a0c[n][3] : 0.f);
        u1.x = f2bf((cb+0 <= ci) ? a1c[n][0] : 0.f);
        u1.y = f2bf((cb+1 <= ci) ? a1c[n][1] : 0.f);
        u1.z = f2bf((cb+2 <= ci) ? a1c[n][2] : 0.f);
        u1.w = f2bf((cb+3 <= ci) ? a1c[n][3] : 0.f);
        *(ushort4*)&Ab0[ci*ST2 + cb] = u0;
        *(ushort4*)&Ab1[ci*ST2 + cb] = u1;
      }
    }
    __syncthreads();

    // ---------------- phase2 ----------------
    {
      bf16x8 esf[8];
#pragma unroll
      for (int n = 0; n < 4; ++n) {
        esf[2*n]   = ldfrag(EsT, n*16,  0, lm, lh);
        esf[2*n+1] = ldfrag(EsT, n*16, 32, lm, lh);
      }
      const u16* Qb = gA ? Qb0 : Qb1;
      const u16* Ab = gA ? Ab0 : Ab1;
      if (!gA) {
#pragma unroll
        for (int n = 0; n < 4; ++n) {
          wfr[2*n]   = ldfrag(WbT, n*16,  0, lm, lh);
          wfr[2*n+1] = ldfrag(WbT, n*16, 32, lm, lh);
        }
      }
      bf16x8 aQ0 = ldfrag(Qb, m0, 0, lm, lh), aQ1 = ldfrag(Qb, m0, 32, lm, lh);
      bf16x8 aA0 = ldfrag(Ab, m0, 0, lm, lh), aA1 = ldfrag(Ab, m0, 32, lm, lh);
      f32x4 oc[4];
#pragma unroll
      for (int n = 0; n < 4; ++n) {
        f32x4 z = {0.f,0.f,0.f,0.f};
        z = __builtin_amdgcn_mfma_f32_16x16x32_bf16(aQ0, wfr[2*n],   z, 0,0,0);
        z = __builtin_amdgcn_mfma_f32_16x16x32_bf16(aQ1, wfr[2*n+1], z, 0,0,0);
        z = __builtin_amdgcn_mfma_f32_16x16x32_bf16(aA0, esf[2*n],   z, 0,0,0);
        z = __builtin_amdgcn_mfma_f32_16x16x32_bf16(aA1, esf[2*n+1], z, 0,0,0);
        oc[n] = z;
      }
      float rr[4];
#pragma unroll
      for (int r = 0; r < 4; ++r) {
        float s = oc[0][r]*oc[0][r] + oc[1][r]*oc[1][r]
                + oc[2][r]*oc[2][r] + oc[3][r]*oc[3][r];
        s += __shfl_xor(s, 1); s += __shfl_xor(s, 2);
        s += __shfl_xor(s, 4); s += __shfl_xor(s, 8);
        rr[r] = rsqrtf(s*(1.f/64.f) + 1e-6f);
      }
      const int ho = (kh*2 + (gA ? 0 : 1))*DD;
#pragma unroll
      for (int n = 0; n < 4; ++n) {
        const int e = n*16 + lm;
        const float ow = onws[e];
#pragma unroll
        for (int r = 0; r < 4; ++r) {
          const size_t idx = (rowbase + cb + r)*(size_t)(NH*DD) + ho + e;
          float val = oc[n][r]*rr[r]*ow;
          u16 hi = f2bf(val);
          qbuf[idx] = hi;
          ylo[idx]  = f2bf(val - bf2f(hi));
        }
      }
      if (!gA) {
        // U' = K^T·negEs; W += U'/64; colnorm partials
        bf16x8 aT0 = ldfrag(KbT, m0, 0, lm, lh), aT1 = ldfrag(KbT, m0, 32, lm, lh);
#pragma unroll
        for (int n = 0; n < 4; ++n) {
          f32x4 z = {0.f,0.f,0.f,0.f};
          z = __builtin_amdgcn_mfma_f32_16x16x32_bf16(aT0, esf[2*n],   z, 0,0,0);
          z = __builtin_amdgcn_mfma_f32_16x16x32_bf16(aT1, esf[2*n+1], z, 0,0,0);
          float p = 0.f;
#pragma unroll
          for (int r = 0; r < 4; ++r) {
            Wreg[n][r] += z[r]*(1.f/64.f);
            p += Wreg[n][r]*Wreg[n][r];
          }
          p += __shfl_xor(p, 16);
          p += __shfl_xor(p, 32);
          if (lh == 0) colp[(n*16 + lm)*4 + (w & 3)] = p;
        }
      }
    }
    __syncthreads();

    // ---------------- finalize ----------------
    if (!gA) {
#pragma unroll
      for (int n = 0; n < 4; ++n) {
        const int e = n*16 + lm;
        float s = colp[e*4+0] + colp[e*4+1] + colp[e*4+2] + colp[e*4+3];
        float rv = 1.f / fmaxf(sqrtf(s), 1e-12f);
        ushort4 u;
#pragma unroll
        for (int r = 0; r < 4; ++r) Wreg[n][r] *= rv;
        u.x = f2bf(Wreg[n][0]); u.y = f2bf(Wreg[n][1]);
        u.z = f2bf(Wreg[n][2]); u.w = f2bf(Wreg[n][3]);
        *(ushort4*)&WbT[e*ST2 + cb] = u;
      }
    }
    if (ch < NCH-1) PROMOTE();
    __syncthreads();
  }
#undef LOAD_PF
#undef PROMOTE
}

// ---------------------------------------------------------------------------
extern "C" void kernel_launch(void* const* d_in, const int* in_sizes, int n_in,
                              void* d_out, int out_size, void* d_ws, size_t ws_size,
                              hipStream_t stream)
{
  (void)in_sizes; (void)n_in; (void)out_size;
  const float* x    = (const float*)d_in[0];
  const float* cosb = (const float*)d_in[1];
  const float* sinb = (const float*)d_in[2];
  const float* Wq   = (const float*)d_in[3];
  const float* Wk   = (const float*)d_in[4];
  const float* Wv   = (const float*)d_in[5];
  const float* Wo   = (const float*)d_in[6];
  const float* lrw  = (const float*)d_in[7];
  const float* lrb  = (const float*)d_in[8];
  const float* onw  = (const float*)d_in[9];
  const float* wis  = (const float*)d_in[10];
  float* out = (float*)d_out;

  const size_t qN   = (size_t)BTOT*NH*DD;      // u16 (q, later y_hi)
  const size_t kN   = (size_t)BTOT*NKV*DD;     // u16
  const size_t wtN  = (size_t)2048*GK;         // u16 per plane
  const size_t wotN = (size_t)1024*GK;         // u16 per plane
  const size_t vN   = (size_t)BTOT*NKV*DD;     // f32
  const size_t etaN = (size_t)BTOT*NKV;        // f32
  const size_t need = (qN*2 + kN + wtN*2 + wotN*2)*2 + (vN + etaN)*4;
  if (ws_size < need) return;

  u16* qbuf  = (u16*)d_ws;          // q, then y_hi
  u16* ylo   = qbuf + qN;           // y_lo
  u16* kbuf  = ylo + qN;
  u16* wth   = kbuf + kN;
  u16* wtl   = wth + wtN;
  u16* woth  = wtl + wtN;
  u16* wotl  = woth + wotN;
  float* vbuf = (float*)(wotl + wotN);
  float* etab = vbuf + vN;

  wt_split<<<dim3(16,16), 256, 0, stream>>>(Wq, wth,           wtl,           NH*DD);
  wt_split<<<dim3( 8,16), 256, 0, stream>>>(Wk, wth + 1024*GK, wtl + 1024*GK, NKV*DD);
  wt_split<<<dim3( 8,16), 256, 0, stream>>>(Wv, wth + 1536*GK, wtl + 1536*GK, NKV*DD);
  wt_split<<<dim3(16,16), 256, 0, stream>>>(Wo, woth,          wotl,          NEMB);

  gemm_qkv<<<dim3(16,128), 256, 0, stream>>>(x, wth, wtl, qbuf, kbuf, vbuf, cosb, sinb);
  eta_kernel<<<BTOT/4, 256, 0, stream>>>(x, lrw, lrb, etab);

  const size_t SMEM = (size_t)(7*64*ST2)*2 + (size_t)(64*4 + 64)*4;  // 72960 B
  hipFuncSetAttribute(reinterpret_cast<const void*>(scan_mfma),
                      hipFuncAttributeMaxDynamicSharedMemorySize, (int)SMEM);
  scan_mfma<<<32, 512, SMEM, stream>>>(qbuf, ylo, kbuf, vbuf, etab, onw, wis);

  gemm_out<<<dim3(8,128), 256, 0, stream>>>(qbuf, ylo, woth, wotl, out);
}